// Round 1
// baseline (1427.401 us; speedup 1.0000x reference)
//
#include <hip/hip_runtime.h>
#include <math.h>

#define C 128
#define N 4096
#define BP 8
#define TN 64
#define TM 64
#define NT (N / TN)
#define SCALE 100.0f   // 1 / SOFTMAX_TEMP
#define OFFSET 60.0f   // fixed softmax offset; logits bounded in [-100,100]

// Kernel 1: inv[b][n] = 1 / max(||desc[b,:,n]||_2, 1e-12)
__global__ __launch_bounds__(256) void knorm_inv(const float* __restrict__ desc,
                                                 float* __restrict__ inv) {
  int n = blockIdx.x * 256 + threadIdx.x;
  int b = blockIdx.y;
  const float* d = desc + (size_t)b * C * N + n;
  float ssq = 0.f;
#pragma unroll 8
  for (int c = 0; c < C; ++c) {
    float v = d[(size_t)c * N];
    ssq = fmaf(v, v, ssq);
  }
  inv[b * N + n] = 1.0f / fmaxf(sqrtf(ssq), 1e-12f);
}

// Kernel 2: fused matcher. One block = one (pair, 64-src-column tile).
// Iterates 64 m-tiles of 64 tgt columns: S = Q^T K (normalization factored
// out as per-m scalar), p = exp(100*s - 60), accumulate 128 desc channels +
// x/y/w/ones. Epilogue in-block.
__global__ __launch_bounds__(256, 1) void kmain(
    const float* __restrict__ coords, const float* __restrict__ wts,
    const float* __restrict__ desc, const float* __restrict__ inv,
    float* __restrict__ out) {
  const int ntile = blockIdx.x;
  const int p = blockIdx.y;
  const int sb = 2 * p, tb = 2 * p + 1;
  const int n0 = ntile * TN;
  const int tid = threadIdx.x;

  __shared__ float qs[C][TN];       // normalized src tile (later: desc numerators)
  __shared__ float vs[C][TM];       // raw tgt desc tile
  __shared__ float ps[TM][TN + 4];  // p-tile, [m][n], stride 68 (conflict pad)
  __shared__ float invt[TM], xs[TM], ys[TM], wls[TM], ones[TM];
  __shared__ float exs[4][TN];      // x/y/w/L numerators for epilogue

  const float* srcd = desc + (size_t)sb * C * N;
  const float* tgtd = desc + (size_t)tb * C * N;
  const float* invs = inv + sb * N;
  const float* invtg = inv + tb * N;
  const float* tcx = coords + (size_t)tb * 2 * N;
  const float* tcy = tcx + N;
  const float* twp = wts + (size_t)tb * N;

  // Load normalized Q tile (float4, coalesced)
  for (int idx4 = tid; idx4 < C * TN / 4; idx4 += 256) {
    int c = idx4 >> 4;
    int t = (idx4 & 15) << 2;
    float4 v = *(const float4*)&srcd[c * N + n0 + t];
    float4 iv = *(const float4*)&invs[n0 + t];
    v.x *= iv.x; v.y *= iv.y; v.z *= iv.z; v.w *= iv.w;
    *(float4*)&qs[c][t] = v;
  }
  if (tid < TM) ones[tid] = 1.0f;

  float accPV[8][4];  // 8 desc channels x 4 n columns
#pragma unroll
  for (int k = 0; k < 8; ++k)
#pragma unroll
    for (int i = 0; i < 4; ++i) accPV[k][i] = 0.f;
  float accEx = 0.f;  // one extra-channel value: (ch = tid>>6, n = tid&63)

  const int ti = tid & 15;   // S phase: n-group
  const int tj = tid >> 4;   // S phase: m-group
  const int cn = ti;         // PV phase: n-group
  const int cc = tj;         // PV phase: channel-group (8 channels each)
  const int ech = tid >> 6, en = tid & 63;
  const float* exsrc = (ech == 0) ? xs : (ech == 1) ? ys : (ech == 2) ? wls : ones;

  for (int m0 = 0; m0 < N; m0 += TM) {
    __syncthreads();  // vs/ps consumed by previous iteration's PV
    for (int idx4 = tid; idx4 < C * TM / 4; idx4 += 256) {
      int c = idx4 >> 4;
      int t = (idx4 & 15) << 2;
      *(float4*)&vs[c][t] = *(const float4*)&tgtd[c * N + m0 + t];
    }
    if (tid < TM) {
      invt[tid] = invtg[m0 + tid];
      xs[tid] = tcx[m0 + tid];
      ys[tid] = tcy[m0 + tid];
      wls[tid] = twp[m0 + tid];
    }
    __syncthreads();

    // ---- S = Q^T * Kraw : 4x4 register micro-tile per thread ----
    float acc[4][4];
#pragma unroll
    for (int i = 0; i < 4; ++i)
#pragma unroll
      for (int j = 0; j < 4; ++j) acc[i][j] = 0.f;

#pragma unroll 4
    for (int c = 0; c < C; ++c) {
      float4 a = *(const float4*)&qs[c][4 * ti];
      float4 b = *(const float4*)&vs[c][4 * tj];
      float av[4] = {a.x, a.y, a.z, a.w};
      float bv[4] = {b.x, b.y, b.z, b.w};
#pragma unroll
      for (int i = 0; i < 4; ++i)
#pragma unroll
        for (int j = 0; j < 4; ++j) acc[i][j] = fmaf(av[i], bv[j], acc[i][j]);
    }

    // ---- p = exp(100 * dot * inv_m - 60) -> ps[m][n] ----
#pragma unroll
    for (int j = 0; j < 4; ++j) {
      float sc = invt[4 * tj + j] * SCALE;
      float4 pr;
      pr.x = __expf(fmaf(acc[0][j], sc, -OFFSET));
      pr.y = __expf(fmaf(acc[1][j], sc, -OFFSET));
      pr.z = __expf(fmaf(acc[2][j], sc, -OFFSET));
      pr.w = __expf(fmaf(acc[3][j], sc, -OFFSET));
      *(float4*)&ps[4 * tj + j][4 * ti] = pr;
    }
    __syncthreads();

    // ---- PV: accPV[k][i] += sum_m vs[cc*8+k][m] * p[n=4*cn+i][m] ----
    // j staggered by channel-group to spread LDS banks (<=2-way = free)
#pragma unroll 2
    for (int jj = 0; jj < TM; jj += 4) {
      int j = (jj + 16 * cc) & (TM - 1);
      float4 p0 = *(const float4*)&ps[j + 0][4 * cn];
      float4 p1 = *(const float4*)&ps[j + 1][4 * cn];
      float4 p2 = *(const float4*)&ps[j + 2][4 * cn];
      float4 p3 = *(const float4*)&ps[j + 3][4 * cn];
#pragma unroll
      for (int k = 0; k < 8; ++k) {
        float4 v = *(const float4*)&vs[cc * 8 + k][j];
        accPV[k][0] += v.x * p0.x + v.y * p1.x + v.z * p2.x + v.w * p3.x;
        accPV[k][1] += v.x * p0.y + v.y * p1.y + v.z * p2.y + v.w * p3.y;
        accPV[k][2] += v.x * p0.z + v.y * p1.z + v.z * p2.z + v.w * p3.z;
        accPV[k][3] += v.x * p0.w + v.y * p1.w + v.z * p2.w + v.w * p3.w;
      }
    }
    // extras: x, y, w, ones(=denominator L)
#pragma unroll 4
    for (int j = 0; j < TM; ++j) accEx = fmaf(exsrc[j], ps[j][en], accEx);
  }

  // ---- epilogue: dump accumulators to LDS, finish per-n ----
  __syncthreads();
#pragma unroll
  for (int k = 0; k < 8; ++k)
#pragma unroll
    for (int i = 0; i < 4; ++i) qs[cc * 8 + k][4 * cn + i] = accPV[k][i];
  exs[ech][en] = accEx;
  __syncthreads();

  if (tid < TN) {
    int n = tid;
    float L = exs[3][n];
    float invL = 1.0f / L;
    float xn = exs[0][n] * invL;
    float yn = exs[1][n] * invL;
    float wn = exs[2][n] * invL;
    // pseudo_desc = dnum / max(||dnum||, tiny); score = <src_desc, pd>/C
    float ssq = 0.f, dotr = 0.f;
    const float* sd = srcd + n0 + n;
#pragma unroll 8
    for (int c = 0; c < C; ++c) {
      float dnum = qs[c][n];
      ssq = fmaf(dnum, dnum, ssq);
      dotr = fmaf(dnum, sd[(size_t)c * N], dotr);
    }
    float nrm = fmaxf(sqrtf(ssq), 1e-30f);
    float score = dotr / (nrm * (float)C);
    float sw = wts[(size_t)sb * N + n0 + n];
    out[(size_t)p * 2 * N + n0 + n] = xn;                                // coords x
    out[(size_t)p * 2 * N + N + n0 + n] = yn;                            // coords y
    out[(size_t)(BP * 2 * N) + (size_t)p * N + n0 + n] =
        0.5f * (score + 1.0f) * sw * wn;                                 // match_weights
  }
}

extern "C" void kernel_launch(void* const* d_in, const int* in_sizes, int n_in,
                              void* d_out, int out_size, void* d_ws, size_t ws_size,
                              hipStream_t stream) {
  const float* coords = (const float*)d_in[0];  // [16][2][4096]
  const float* wts = (const float*)d_in[1];     // [16][1][4096]
  const float* desc = (const float*)d_in[2];    // [16][128][4096]
  float* out = (float*)d_out;                   // [8][2][4096] ++ [8][1][4096]
  float* inv = (float*)d_ws;                    // [16][4096] inv-norms (256 KB)

  knorm_inv<<<dim3(N / 256, 16), 256, 0, stream>>>(desc, inv);
  kmain<<<dim3(NT, BP), 256, 0, stream>>>(coords, wts, desc, inv, out);
}

// Round 2
// 1253.207 us; speedup vs baseline: 1.1390x; 1.1390x over previous
//
#include <hip/hip_runtime.h>
#include <math.h>

#define C 128
#define N 4096
#define BP 8
#define TN 64
#define TM 32

typedef __attribute__((ext_vector_type(8))) short bf16x8;
typedef __attribute__((ext_vector_type(16))) float f32x16;

__device__ __forceinline__ unsigned short bf16rnd(float x) {
  unsigned u = __float_as_uint(x);
  u += 0x7fffu + ((u >> 16) & 1u);
  return (unsigned short)(u >> 16);
}
__device__ __forceinline__ float bf16up(unsigned short h) {
  return __uint_as_float(((unsigned)h) << 16);
}

// Kernel 1: inv[b][n] = 1 / max(||desc[b,:,n]||_2, 1e-12)
__global__ __launch_bounds__(256) void knorm_inv(const float* __restrict__ desc,
                                                 float* __restrict__ inv) {
  int n = blockIdx.x * 256 + threadIdx.x;
  int b = blockIdx.y;
  const float* d = desc + (size_t)b * C * N + n;
  float ssq = 0.f;
#pragma unroll 8
  for (int c = 0; c < C; ++c) {
    float v = d[(size_t)c * N];
    ssq = fmaf(v, v, ssq);
  }
  inv[b * N + n] = 1.0f / fmaxf(sqrtf(ssq), 1e-12f);
}

// Kernel 2: MFMA fused matcher.
// Block = (pair, 64 src columns), 128 threads = 2 waves, wave owns n-slab 32.
// QK^T: S^T[m][n] = Vnorm^T · Qnorm via 3x hi/lo bf16 MFMA (fp32-grade logits).
// P = exp(100*S - 60) (bounded logits -> fixed-offset softmax, no rescaling).
// PV: out^T[c][n] += V_hi · P_{hi,lo} over 5 c-tiles (128 desc + x/y/w/1).
// All LDS operands stored in FRAGMENT ORDER (lane-contiguous ds_read_b128).
__global__ __launch_bounds__(128, 2) void kmain(
    const float* __restrict__ coords, const float* __restrict__ wtsp,
    const float* __restrict__ desc, const float* __restrict__ inv,
    float* __restrict__ out) {
  const int ntile = blockIdx.x;
  const int p = blockIdx.y;
  const int sb = 2 * p, tb = 2 * p + 1;
  const int n0 = ntile * TN;
  const int tid = threadIdx.x;
  const int w = tid >> 6;   // wave id 0/1
  const int ln = tid & 63;  // lane
  const int l31 = ln & 31;
  const int h = ln >> 5;    // lane half

  // fragment-order LDS: frag = 512 shorts (64 lanes x 8 bf16 = 16B/lane)
  __shared__ __align__(16) short VmcHi[8 * 512];   // QK^T A (normalized tgt), hi
  __shared__ __align__(16) short VmcLo[8 * 512];   // lo
  __shared__ __align__(16) short VcmHi[10 * 512];  // PV A (raw tgt + extras), hi only
  __shared__ __align__(16) short PHi[2 * 2 * 512]; // per-wave P frags, hi
  __shared__ __align__(16) short PLo[2 * 2 * 512]; // lo

  const float* srcd = desc + (size_t)sb * C * N;
  const float* tgtd = desc + (size_t)tb * C * N;
  const float* invtg = inv + tb * N;
  const float* tcx = coords + (size_t)tb * 2 * N;
  const float* tcy = tcx + N;
  const float* twp = wtsp + (size_t)tb * N;

  const int nn = n0 + 32 * w + l31;  // this lane's src column

  // ---- Q setup: pass 1 = sum of squares (lane holds octet-parity-h c's) ----
  float ssq = 0.f;
#pragma unroll
  for (int k = 0; k < 8; ++k) {
    int cb = 16 * k + 8 * h;
#pragma unroll
    for (int i = 0; i < 8; ++i) {
      float v = srcd[(size_t)(cb + i) * N + nn];
      ssq = fmaf(v, v, ssq);
    }
  }
  ssq += __shfl_xor(ssq, 32);
  float invs = 1.0f / fmaxf(sqrtf(ssq), 1e-12f);

  // pass 2: build resident B-fragments Qh/Ql (k-step x hi/lo)
  bf16x8 Qh[8], Ql[8];
#pragma unroll
  for (int k = 0; k < 8; ++k) {
    int cb = 16 * k + 8 * h;
    bf16x8 qh, ql;
#pragma unroll
    for (int i = 0; i < 8; ++i) {
      float v = srcd[(size_t)(cb + i) * N + nn] * invs;
      unsigned short hs = bf16rnd(v);
      unsigned short ls = bf16rnd(v - bf16up(hs));
      qh[i] = (short)hs;
      ql[i] = (short)ls;
    }
    Qh[k] = qh;
    Ql[k] = ql;
  }

  // zero tile-4 (extras) frag region once: garbage rows 132..159 must be finite 0
  {
    int* z = (int*)&VcmHi[8 * 512];
    for (int i = tid; i < 512; i += 128) z[i] = 0;
  }

  f32x16 acc[5];
#pragma unroll
  for (int t = 0; t < 5; ++t)
#pragma unroll
    for (int r = 0; r < 16; ++r) acc[t][r] = 0.f;

  for (int m0 = 0; m0 < N; m0 += TM) {
    __syncthreads();  // prior iter's fragment reads done before restaging

    // ---- stage Vmc = normalized tgt, QK^T-A fragment order ----
    {
      int mm = m0 + l31;
      float invm = invtg[mm];
#pragma unroll
      for (int k = 0; k < 4; ++k) {
        int kk = 2 * k + w;
        int cb = 16 * kk + 8 * h;
        unsigned short hs[8], ls[8];
#pragma unroll
        for (int i = 0; i < 8; ++i) {
          float v = tgtd[(size_t)(cb + i) * N + mm] * invm;
          hs[i] = bf16rnd(v);
          ls[i] = bf16rnd(v - bf16up(hs[i]));
        }
        int4 ph, pl;
        ph.x = hs[0] | (hs[1] << 16); ph.y = hs[2] | (hs[3] << 16);
        ph.z = hs[4] | (hs[5] << 16); ph.w = hs[6] | (hs[7] << 16);
        pl.x = ls[0] | (ls[1] << 16); pl.y = ls[2] | (ls[3] << 16);
        pl.z = ls[4] | (ls[5] << 16); pl.w = ls[6] | (ls[7] << 16);
        *(int4*)&VmcHi[kk * 512 + ln * 8] = ph;
        *(int4*)&VmcLo[kk * 512 + ln * 8] = pl;
      }
    }

    // ---- stage Vcm rows 0..127 = raw tgt desc, PV-A fragment order ----
#pragma unroll
    for (int it = 0; it < 8; ++it) {
      int e = tid + 128 * it;  // 0..1023 float4s
      int c = e >> 3, mq = e & 7;
      float4 v = *(const float4*)&tgtd[(size_t)c * N + m0 + 4 * mq];
      int f = (c >> 5) * 2 + (mq >> 2);
      int slot = (c & 31) + 32 * ((mq >> 1) & 1);
      int2 pk;
      pk.x = bf16rnd(v.x) | (bf16rnd(v.y) << 16);
      pk.y = bf16rnd(v.z) | (bf16rnd(v.w) << 16);
      *(int2*)&VcmHi[f * 512 + slot * 8 + (mq & 1) * 4] = pk;
    }

    // ---- extras rows: x,y,w,1 -> tile-4 frags (8,9), slots 0..3 / 32..35 ----
    if (tid < 16) {
      int r = tid & 3, hh = (tid >> 2) & 1, s = tid >> 3;
      int mb = m0 + 16 * s + 8 * hh;
      const float* rp = (r == 0) ? tcx : (r == 1) ? tcy : twp;
      unsigned short hs[8];
#pragma unroll
      for (int i = 0; i < 8; ++i) {
        float v = (r == 3) ? 1.0f : rp[mb + i];
        hs[i] = bf16rnd(v);
      }
      int4 pk;
      pk.x = hs[0] | (hs[1] << 16); pk.y = hs[2] | (hs[3] << 16);
      pk.z = hs[4] | (hs[5] << 16); pk.w = hs[6] | (hs[7] << 16);
      *(int4*)&VcmHi[(8 + s) * 512 + (r + 32 * hh) * 8] = pk;
    }

    __syncthreads();

    // ---- QK^T: S^T = Vnorm^T * Qnorm, 3-MFMA hi/lo split ----
    f32x16 S;
#pragma unroll
    for (int r = 0; r < 16; ++r) S[r] = 0.f;
#pragma unroll
    for (int k = 0; k < 8; ++k) {
      bf16x8 ah = *(const bf16x8*)&VmcHi[k * 512 + ln * 8];
      bf16x8 al = *(const bf16x8*)&VmcLo[k * 512 + ln * 8];
      S = __builtin_amdgcn_mfma_f32_32x32x16_bf16(al, Qh[k], S, 0, 0, 0);
      S = __builtin_amdgcn_mfma_f32_32x32x16_bf16(ah, Ql[k], S, 0, 0, 0);
      S = __builtin_amdgcn_mfma_f32_32x32x16_bf16(ah, Qh[k], S, 0, 0, 0);
    }

    // ---- P = exp(100*S-60), hi/lo, write to own-wave P frags (no barrier) ----
#pragma unroll
    for (int q = 0; q < 4; ++q) {
      unsigned short ph[4], pl[4];
#pragma unroll
      for (int i = 0; i < 4; ++i) {
        float pv = __expf(fmaf(S[4 * q + i], 100.0f, -60.0f));
        ph[i] = bf16rnd(pv);
        pl[i] = bf16rnd(pv - bf16up(ph[i]));
      }
      int base = w * 1024 + (q >> 1) * 512 + (l31 + 32 * (q & 1)) * 8 + h * 4;
      int2 a, b;
      a.x = ph[0] | (ph[1] << 16); a.y = ph[2] | (ph[3] << 16);
      b.x = pl[0] | (pl[1] << 16); b.y = pl[2] | (pl[3] << 16);
      *(int2*)&PHi[base] = a;
      *(int2*)&PLo[base] = b;
    }

    // ---- PV: acc[t] += Vcm[t] * (Phi + Plo), same-wave P (lgkmcnt-ordered) ----
#pragma unroll
    for (int s2 = 0; s2 < 2; ++s2) {
      bf16x8 bh = *(const bf16x8*)&PHi[w * 1024 + s2 * 512 + ln * 8];
      bf16x8 bl = *(const bf16x8*)&PLo[w * 1024 + s2 * 512 + ln * 8];
#pragma unroll
      for (int t = 0; t < 5; ++t) {
        bf16x8 va = *(const bf16x8*)&VcmHi[(2 * t + s2) * 512 + ln * 8];
        acc[t] = __builtin_amdgcn_mfma_f32_32x32x16_bf16(va, bh, acc[t], 0, 0, 0);
        acc[t] = __builtin_amdgcn_mfma_f32_32x32x16_bf16(va, bl, acc[t], 0, 0, 0);
      }
    }
  }

  // ---- epilogue (registers + global only; no block sync needed) ----
  float ssqd = 0.f, dotr = 0.f;
#pragma unroll
  for (int t = 0; t < 4; ++t) {
#pragma unroll
    for (int r = 0; r < 16; ++r) {
      int c = 32 * t + (r & 3) + 8 * (r >> 2) + 4 * h;
      float d = acc[t][r];
      ssqd = fmaf(d, d, ssqd);
      dotr = fmaf(d, srcd[(size_t)c * N + nn], dotr);
    }
  }
  ssqd += __shfl_xor(ssqd, 32);
  dotr += __shfl_xor(dotr, 32);
  if (h == 0) {
    float x = acc[4][0], y = acc[4][1], wv = acc[4][2], L = acc[4][3];
    float invL = 1.0f / L;
    float nrm = fmaxf(sqrtf(ssqd), 1e-30f);
    float score = dotr / (nrm * 128.0f);
    float sw = wtsp[(size_t)sb * N + nn];
    out[(size_t)p * 2 * N + nn] = x * invL;
    out[(size_t)p * 2 * N + N + nn] = y * invL;
    out[(size_t)(BP * 2 * N) + (size_t)p * N + nn] =
        0.5f * (score + 1.0f) * sw * wv * invL;
  }
}

extern "C" void kernel_launch(void* const* d_in, const int* in_sizes, int n_in,
                              void* d_out, int out_size, void* d_ws, size_t ws_size,
                              hipStream_t stream) {
  const float* coords = (const float*)d_in[0];  // [16][2][4096]
  const float* wts = (const float*)d_in[1];     // [16][1][4096]
  const float* desc = (const float*)d_in[2];    // [16][128][4096]
  float* out = (float*)d_out;                   // [8][2][4096] ++ [8][1][4096]
  float* inv = (float*)d_ws;                    // [16][4096] inv-norms

  knorm_inv<<<dim3(N / 256, 16), 256, 0, stream>>>(desc, inv);
  kmain<<<dim3(N / TN, BP), 128, 0, stream>>>(coords, wts, desc, inv, out);
}

// Round 3
// 293.780 us; speedup vs baseline: 4.8587x; 4.2658x over previous
//
#include <hip/hip_runtime.h>
#include <math.h>

#define C 128
#define N 4096
#define BP 8
#define TN 64

typedef __attribute__((ext_vector_type(8))) short bf16x8;
typedef __attribute__((ext_vector_type(16))) float f32x16;

// LDS layout in shorts (60 KB total -> 2 blocks/CU)
#define OFF_VMH 0        // QK^T A hi: 2 subtiles x 8 frags x 512
#define OFF_VML 8192     // QK^T A lo
#define OFF_VCM 16384    // PV A hi:   2 subtiles x 10 frags x 512
#define OFF_PH  26624    // P hi:      4 waves x 2 frags x 512
#define LDS_SHORTS 30720

__device__ __forceinline__ unsigned short bf16rnd(float x) {
  unsigned u = __float_as_uint(x);
  u += 0x7fffu + ((u >> 16) & 1u);
  return (unsigned short)(u >> 16);
}
__device__ __forceinline__ float bf16up(unsigned short h) {
  return __uint_as_float(((unsigned)h) << 16);
}
// pack RNE(x),RNE(y) -> [bf16(x) | bf16(y)<<16] via v_perm
__device__ __forceinline__ int rne2(float x, float y) {
  unsigned ux = __float_as_uint(x); ux += 0x7fffu + ((ux >> 16) & 1u);
  unsigned uy = __float_as_uint(y); uy += 0x7fffu + ((uy >> 16) & 1u);
  return (int)__builtin_amdgcn_perm(uy, ux, 0x07060302u);
}
// pack trunc(x),trunc(y) (1 instr)
__device__ __forceinline__ int trunc2(float x, float y) {
  return (int)__builtin_amdgcn_perm(__float_as_uint(y), __float_as_uint(x), 0x07060302u);
}
__device__ __forceinline__ float truncres(float x) {  // x - bf16up(trunc(x))
  return x - __uint_as_float(__float_as_uint(x) & 0xffff0000u);
}

// Kernel 1: inv[b][n] = 1 / max(||desc[b,:,n]||_2, 1e-12)
__global__ __launch_bounds__(256) void knorm_inv(const float* __restrict__ desc,
                                                 float* __restrict__ inv) {
  int n = blockIdx.x * 256 + threadIdx.x;
  int b = blockIdx.y;
  const float* d = desc + (size_t)b * C * N + n;
  float ssq = 0.f;
#pragma unroll 8
  for (int c = 0; c < C; ++c) {
    float v = d[(size_t)c * N];
    ssq = fmaf(v, v, ssq);
  }
  inv[b * N + n] = 1.0f / fmaxf(sqrtf(ssq), 1e-12f);
}

// Kernel 2: MFMA fused matcher, 4 waves/block, 2-way m-split across wave-pairs.
// wave w: wn=w&1 -> n-slab (32 cols), st=w>>1 -> m-subtile (32 m's per iter).
__global__ __launch_bounds__(256, 2) void kmain(
    const float* __restrict__ coords, const float* __restrict__ wtsp,
    const float* __restrict__ desc, const float* __restrict__ inv,
    float* __restrict__ out) {
  const int ntile = blockIdx.x;
  const int p = blockIdx.y;
  const int sb = 2 * p, tb = 2 * p + 1;
  const int n0 = ntile * TN;
  const int tid = threadIdx.x;
  const int w = tid >> 6;
  const int ln = tid & 63;
  const int l31 = ln & 31;
  const int h = ln >> 5;
  const int wn = w & 1;        // n-slab within block
  const int st = w >> 1;       // m-subtile
  const int pt = wn * 64 + ln; // pair-thread id 0..127

  __shared__ __align__(16) short L[LDS_SHORTS];

  const float* srcd = desc + (size_t)sb * C * N;
  const float* tgtd = desc + (size_t)tb * C * N;
  const float* invtg = inv + tb * N;
  const float* tcx = coords + (size_t)tb * 2 * N;
  const float* tcy = tcx + N;
  const float* twp = wtsp + (size_t)tb * N;

  const int nn = n0 + 32 * wn + l31;  // this lane's src column

  // ---- Q setup: sum of squares, then resident B-fragments Qh/Ql ----
  float ssq = 0.f;
#pragma unroll
  for (int k = 0; k < 8; ++k) {
    int cb = 16 * k + 8 * h;
#pragma unroll
    for (int i = 0; i < 8; ++i) {
      float v = srcd[(size_t)(cb + i) * N + nn];
      ssq = fmaf(v, v, ssq);
    }
  }
  ssq += __shfl_xor(ssq, 32);
  float invs = 1.0f / fmaxf(sqrtf(ssq), 1e-12f);

  bf16x8 Qh[8], Ql[8];
#pragma unroll
  for (int k = 0; k < 8; ++k) {
    int cb = 16 * k + 8 * h;
    bf16x8 qh, ql;
#pragma unroll
    for (int i = 0; i < 8; ++i) {
      float v = srcd[(size_t)(cb + i) * N + nn] * invs;
      unsigned short hs = bf16rnd(v);
      unsigned short ls = bf16rnd(v - bf16up(hs));
      qh[i] = (short)hs;
      ql[i] = (short)ls;
    }
    Qh[k] = qh;
    Ql[k] = ql;
  }

  // zero extras frag regions (rows 132..159 must be 0), both subtiles
  {
    int* z = (int*)&L[OFF_VCM];
    for (int i = tid; i < 1024; i += 256) {
      int sI = i >> 9, j = i & 511;
      z[sI * 2560 + 2048 + j] = 0;
    }
  }

  f32x16 acc[5];
#pragma unroll
  for (int t = 0; t < 5; ++t)
#pragma unroll
    for (int r = 0; r < 16; ++r) acc[t][r] = 0.f;

  // extras row pointer (fixed per thread)
  const int er = pt & 3, ehh = (pt >> 2) & 1, esf = pt >> 3;
  const float* erp = (er == 0) ? tcx : (er == 1) ? tcy : twp;

  // ---- prefetch registers ----
  float vm[32];
  float invm = 0.f;
  float4 exv0 = make_float4(1, 1, 1, 1), exv1 = exv0;

  auto prefetch = [&](int ms0) {
#pragma unroll
    for (int k = 0; k < 4; ++k) {
      int cb = 16 * (2 * k + wn) + 8 * h;
#pragma unroll
      for (int i = 0; i < 8; ++i)
        vm[k * 8 + i] = tgtd[(size_t)(cb + i) * N + ms0 + l31];
    }
    invm = invtg[ms0 + l31];
    if (pt < 16 && er < 3) {
      int mb = ms0 + 16 * esf + 8 * ehh;
      exv0 = *(const float4*)&erp[mb];
      exv1 = *(const float4*)&erp[mb + 4];
    }
  };

  prefetch(32 * st);

  for (int m0 = 0; m0 < N; m0 += 64) {
    const int ms0 = m0 + 32 * st;

    // ===== convert phase (uses prefetched regs) =====
    // issue Vcm raw loads first (latency hidden behind Vmc convert below)
    float4 vc[8];
#pragma unroll
    for (int it = 0; it < 8; ++it) {
      int e = pt + 128 * it, c = e >> 3, mq = e & 7;
      vc[it] = *(const float4*)&tgtd[(size_t)c * N + ms0 + 4 * mq];
    }

    // Vmc: normalized tgt, trunc hi/lo, fragment order
#pragma unroll
    for (int k = 0; k < 4; ++k) {
      int kk = 2 * k + wn;
      int hw[4], lw[4];
#pragma unroll
      for (int j = 0; j < 4; ++j) {
        float v0 = vm[k * 8 + 2 * j] * invm;
        float v1 = vm[k * 8 + 2 * j + 1] * invm;
        hw[j] = trunc2(v0, v1);
        lw[j] = trunc2(truncres(v0), truncres(v1));
      }
      *(int4*)&L[OFF_VMH + st * 4096 + kk * 512 + ln * 8] =
          make_int4(hw[0], hw[1], hw[2], hw[3]);
      *(int4*)&L[OFF_VML + st * 4096 + kk * 512 + ln * 8] =
          make_int4(lw[0], lw[1], lw[2], lw[3]);
    }

    // Vcm: raw tgt, RNE hi, PV fragment order
#pragma unroll
    for (int it = 0; it < 8; ++it) {
      int e = pt + 128 * it, c = e >> 3, mq = e & 7;
      float4 v = vc[it];
      int f = (c >> 5) * 2 + (mq >> 2);
      int slot = (c & 31) + 32 * ((mq >> 1) & 1);
      int2 pk;
      pk.x = rne2(v.x, v.y);
      pk.y = rne2(v.z, v.w);
      *(int2*)&L[OFF_VCM + st * 5120 + f * 512 + slot * 8 + (mq & 1) * 4] = pk;
    }

    // extras rows x,y,w,1 -> frags 8,9 of this subtile
    if (pt < 16) {
      int4 pk;
      pk.x = rne2(exv0.x, exv0.y);
      pk.y = rne2(exv0.z, exv0.w);
      pk.z = rne2(exv1.x, exv1.y);
      pk.w = rne2(exv1.z, exv1.w);
      *(int4*)&L[OFF_VCM + st * 5120 + (8 + esf) * 512 + (er + 32 * ehh) * 8] = pk;
    }

    __syncthreads();

    // prefetch next iteration's tile (overlaps compute below)
    if (m0 + 64 < N) prefetch(ms0 + 64);

    // ===== compute phase =====
    // QK^T: S^T = Vnorm^T * Qnorm, 3-MFMA hi/lo split
    f32x16 S;
#pragma unroll
    for (int r = 0; r < 16; ++r) S[r] = 0.f;
    const short* vmh = &L[OFF_VMH + st * 4096];
    const short* vml = &L[OFF_VML + st * 4096];
#pragma unroll
    for (int k = 0; k < 8; ++k) {
      bf16x8 ah = *(const bf16x8*)&vmh[k * 512 + ln * 8];
      bf16x8 al = *(const bf16x8*)&vml[k * 512 + ln * 8];
      S = __builtin_amdgcn_mfma_f32_32x32x16_bf16(al, Qh[k], S, 0, 0, 0);
      S = __builtin_amdgcn_mfma_f32_32x32x16_bf16(ah, Ql[k], S, 0, 0, 0);
      S = __builtin_amdgcn_mfma_f32_32x32x16_bf16(ah, Qh[k], S, 0, 0, 0);
    }

    // P = exp(100*S - 60), RNE bf16 hi only, own-wave frags (no barrier)
#pragma unroll
    for (int q = 0; q < 4; ++q) {
      float p0 = __expf(fmaf(S[4 * q + 0], 100.0f, -60.0f));
      float p1 = __expf(fmaf(S[4 * q + 1], 100.0f, -60.0f));
      float p2 = __expf(fmaf(S[4 * q + 2], 100.0f, -60.0f));
      float p3 = __expf(fmaf(S[4 * q + 3], 100.0f, -60.0f));
      int2 a;
      a.x = rne2(p0, p1);
      a.y = rne2(p2, p3);
      *(int2*)&L[OFF_PH + w * 1024 + (q >> 1) * 512 + (l31 + 32 * (q & 1)) * 8 +
                 h * 4] = a;
    }

    // PV: acc[t] += Vcm[t] * Phi (same-wave P, lgkmcnt-ordered)
#pragma unroll
    for (int s2 = 0; s2 < 2; ++s2) {
      bf16x8 bh = *(const bf16x8*)&L[OFF_PH + w * 1024 + s2 * 512 + ln * 8];
#pragma unroll
      for (int t = 0; t < 5; ++t) {
        bf16x8 va = *(const bf16x8*)&L[OFF_VCM + st * 5120 + (2 * t + s2) * 512 + ln * 8];
        acc[t] = __builtin_amdgcn_mfma_f32_32x32x16_bf16(va, bh, acc[t], 0, 0, 0);
      }
    }

    __syncthreads();
  }

  // ---- cross-subtile accumulator reduction ----
  float* red = (float*)&L[0];
  if (st == 1) {
#pragma unroll
    for (int t = 0; t < 5; ++t)
#pragma unroll
      for (int r = 0; r < 16; ++r)
        red[wn * 5120 + t * 1024 + r * 64 + ln] = acc[t][r];
  }
  __syncthreads();

  if (st == 0) {
#pragma unroll
    for (int t = 0; t < 5; ++t)
#pragma unroll
      for (int r = 0; r < 16; ++r)
        acc[t][r] += red[wn * 5120 + t * 1024 + r * 64 + ln];

    // ---- epilogue ----
    float ssqd = 0.f, dotr = 0.f;
#pragma unroll
    for (int t = 0; t < 4; ++t) {
#pragma unroll
      for (int r = 0; r < 16; ++r) {
        int c = 32 * t + (r & 3) + 8 * (r >> 2) + 4 * h;
        float d = acc[t][r];
        ssqd = fmaf(d, d, ssqd);
        dotr = fmaf(d, srcd[(size_t)c * N + nn], dotr);
      }
    }
    ssqd += __shfl_xor(ssqd, 32);
    dotr += __shfl_xor(dotr, 32);
    if (h == 0) {
      float x = acc[4][0], y = acc[4][1], wv = acc[4][2], Ld = acc[4][3];
      float invL = 1.0f / Ld;
      float nrm = fmaxf(sqrtf(ssqd), 1e-30f);
      float score = dotr / (nrm * 128.0f);
      float sw = wtsp[(size_t)sb * N + nn];
      out[(size_t)p * 2 * N + nn] = x * invL;
      out[(size_t)p * 2 * N + N + nn] = y * invL;
      out[(size_t)(BP * 2 * N) + (size_t)p * N + nn] =
          0.5f * (score + 1.0f) * sw * wv * invL;
    }
  }
}

extern "C" void kernel_launch(void* const* d_in, const int* in_sizes, int n_in,
                              void* d_out, int out_size, void* d_ws, size_t ws_size,
                              hipStream_t stream) {
  const float* coords = (const float*)d_in[0];  // [16][2][4096]
  const float* wts = (const float*)d_in[1];     // [16][1][4096]
  const float* desc = (const float*)d_in[2];    // [16][128][4096]
  float* out = (float*)d_out;                   // [8][2][4096] ++ [8][1][4096]
  float* inv = (float*)d_ws;                    // [16][4096] inv-norms

  knorm_inv<<<dim3(N / 256, 16), 256, 0, stream>>>(desc, inv);
  kmain<<<dim3(N / TN, BP), 256, 0, stream>>>(coords, wts, desc, inv, out);
}

// Round 4
// 242.312 us; speedup vs baseline: 5.8907x; 1.2124x over previous
//
#include <hip/hip_runtime.h>
#include <math.h>

#define C 128
#define N 4096
#define BP 8
#define TN 64

typedef __attribute__((ext_vector_type(8))) short bf16x8;
typedef __attribute__((ext_vector_type(16))) float f32x16;

// ---------- ws layout ----------
// [0, 64KB)            inv-norms  float[16][4096] (odd b only used)
// [64KB, 64KB+27.3MB)  fragment blob: [pair][mt=128][26 frags][1KB]
//   frag 0..7  = Vm hi (QK^T A, normalized tgt, trunc-hi)
//   frag 8..15 = Vm lo
//   frag 16..23= Vcm hi (PV A, raw tgt desc, RNE)
//   frag 24..25= extras rows x/y/w/1 (+ zero padding rows)
#define PREP_OFF 65536
#define FRAGS_PER_MT 26
#define BLOB_BYTES ((size_t)BP * 128 * FRAGS_PER_MT * 1024)

__device__ __forceinline__ unsigned short bf16rnd(float x) {
  unsigned u = __float_as_uint(x);
  u += 0x7fffu + ((u >> 16) & 1u);
  return (unsigned short)(u >> 16);
}
__device__ __forceinline__ float bf16up(unsigned short h) {
  return __uint_as_float(((unsigned)h) << 16);
}
__device__ __forceinline__ int rne2(float x, float y) {
  unsigned ux = __float_as_uint(x); ux += 0x7fffu + ((ux >> 16) & 1u);
  unsigned uy = __float_as_uint(y); uy += 0x7fffu + ((uy >> 16) & 1u);
  return (int)__builtin_amdgcn_perm(uy, ux, 0x07060302u);
}
__device__ __forceinline__ int trunc2(float x, float y) {
  return (int)__builtin_amdgcn_perm(__float_as_uint(y), __float_as_uint(x), 0x07060302u);
}
__device__ __forceinline__ float truncres(float x) {
  return x - __uint_as_float(__float_as_uint(x) & 0xffff0000u);
}

// Kernel 1: inv[b][n] = 1/max(||desc[b,:,n]||,1e-12), tgt batches (odd) only
__global__ __launch_bounds__(256) void knorm_inv(const float* __restrict__ desc,
                                                 float* __restrict__ inv) {
  int n = blockIdx.x * 256 + threadIdx.x;
  int b = 2 * blockIdx.y + 1;
  const float* d = desc + (size_t)b * C * N + n;
  float ssq = 0.f;
#pragma unroll 8
  for (int c = 0; c < C; ++c) {
    float v = d[(size_t)c * N];
    ssq = fmaf(v, v, ssq);
  }
  inv[b * N + n] = 1.0f / fmaxf(sqrtf(ssq), 1e-12f);
}

// Kernel 1b: one-shot conversion of tgt tiles into fragment-order bf16 blobs.
// Block = (mt, pair); converts the 32-m subtile once (kmain re-reads it 64x).
__global__ __launch_bounds__(256) void kprep(
    const float* __restrict__ coords, const float* __restrict__ wtsp,
    const float* __restrict__ desc, const float* __restrict__ inv,
    unsigned char* __restrict__ blob) {
  const int mt = blockIdx.x;  // 0..127
  const int p = blockIdx.y;   // 0..7
  const int tb = 2 * p + 1;
  const int m0 = mt * 32;
  const int t = threadIdx.x;
  const int ln = t & 63, l31 = ln & 31, h = ln >> 5;
  const int kpart = t >> 6;  // 0..3

  const float* tgtd = desc + (size_t)tb * C * N;
  unsigned char* bl = blob + ((size_t)(p * 128 + mt) * FRAGS_PER_MT) * 1024;

  const float invm = inv[tb * N + m0 + l31];

  // Vm hi/lo frags 0..15 (QK^T A fragment order)
#pragma unroll
  for (int kx = 0; kx < 2; ++kx) {
    int kk = kpart * 2 + kx;
    int cb = 16 * kk + 8 * h;
    int hw[4], lw[4];
#pragma unroll
    for (int j = 0; j < 4; ++j) {
      float v0 = tgtd[(size_t)(cb + 2 * j) * N + m0 + l31] * invm;
      float v1 = tgtd[(size_t)(cb + 2 * j + 1) * N + m0 + l31] * invm;
      hw[j] = trunc2(v0, v1);
      lw[j] = trunc2(truncres(v0), truncres(v1));
    }
    *(int4*)(bl + (size_t)kk * 1024 + ln * 16) = make_int4(hw[0], hw[1], hw[2], hw[3]);
    *(int4*)(bl + (size_t)(8 + kk) * 1024 + ln * 16) = make_int4(lw[0], lw[1], lw[2], lw[3]);
  }

  // Vcm desc frags 16..23 (PV A fragment order, RNE hi)
#pragma unroll
  for (int it = 0; it < 4; ++it) {
    int e = t + 256 * it;  // 0..1023 float4 granules
    int c = e >> 3, mq = e & 7;
    float4 v = *(const float4*)&tgtd[(size_t)c * N + m0 + 4 * mq];
    int f = (c >> 5) * 2 + (mq >> 2);
    int slot = (c & 31) + 32 * ((mq >> 1) & 1);
    int2 pk;
    pk.x = rne2(v.x, v.y);
    pk.y = rne2(v.z, v.w);
    *(int2*)(bl + (size_t)(16 + f) * 1024 + slot * 16 + (mq & 1) * 8) = pk;
  }

  // extras frags 24,25: rows 0..3 = x,y,w,1; all other rows zero
  if (t < 128) {
    int fe = t >> 6, slot = t & 63, r = slot & 31, hh = slot >> 5;
    int4 pk = make_int4(0, 0, 0, 0);
    if (r < 4) {
      const float* rp = (r == 0)   ? coords + (size_t)tb * 2 * N
                        : (r == 1) ? coords + (size_t)tb * 2 * N + N
                                   : wtsp + (size_t)tb * N;
      int mb = m0 + 16 * fe + 8 * hh;
      float v[8];
#pragma unroll
      for (int i = 0; i < 8; ++i) v[i] = (r == 3) ? 1.0f : rp[mb + i];
      pk.x = rne2(v[0], v[1]);
      pk.y = rne2(v[2], v[3]);
      pk.z = rne2(v[4], v[5]);
      pk.w = rne2(v[6], v[7]);
    }
    *(int4*)(bl + (size_t)(24 + fe) * 1024 + slot * 16) = pk;
  }
}

// ---------- fast main kernel: DMA staging via global_load_lds ----------
// LDS: 52 V-frags (2 subtiles x 26) then 8KB P region. 60KB -> 2 blocks/CU.
#define LDS_V_SHORTS (52 * 512)
#define OFF_P LDS_V_SHORTS
#define LDS_SHORTS (LDS_V_SHORTS + 4 * 1024)

__global__ __launch_bounds__(256, 2) void kmain(
    const float* __restrict__ wtsp, const float* __restrict__ desc,
    const unsigned char* __restrict__ blob, float* __restrict__ out) {
  const int ntile = blockIdx.x;
  const int p = blockIdx.y;
  const int sb = 2 * p;
  const int n0 = ntile * TN;
  const int tid = threadIdx.x;
  const int w = tid >> 6;
  const int ln = tid & 63;
  const int l31 = ln & 31;
  const int h = ln >> 5;
  const int wn = w & 1;   // n-slab
  const int st = w >> 1;  // m-subtile

  __shared__ __align__(16) short L[LDS_SHORTS];

  const float* srcd = desc + (size_t)sb * C * N;
  const unsigned char* wblob = blob + (size_t)p * 128 * FRAGS_PER_MT * 1024;
  const int nn = n0 + 32 * wn + l31;

  // ---- Q setup: norm + resident B-fragments (trunc hi/lo) ----
  float ssq = 0.f;
#pragma unroll
  for (int k = 0; k < 8; ++k) {
    int cb = 16 * k + 8 * h;
#pragma unroll
    for (int i = 0; i < 8; ++i) {
      float v = srcd[(size_t)(cb + i) * N + nn];
      ssq = fmaf(v, v, ssq);
    }
  }
  ssq += __shfl_xor(ssq, 32);
  float invs = 1.0f / fmaxf(sqrtf(ssq), 1e-12f);

  bf16x8 Qh[8], Ql[8];
#pragma unroll
  for (int k = 0; k < 8; ++k) {
    int cb = 16 * k + 8 * h;
    bf16x8 qh, ql;
#pragma unroll
    for (int i = 0; i < 8; ++i) {
      float v = srcd[(size_t)(cb + i) * N + nn] * invs;
      unsigned short hs = bf16rnd(v);
      unsigned short ls = bf16rnd(v - bf16up(hs));
      qh[i] = (short)hs;
      ql[i] = (short)ls;
    }
    Qh[k] = qh;
    Ql[k] = ql;
  }

  f32x16 acc[5];
#pragma unroll
  for (int t = 0; t < 5; ++t)
#pragma unroll
    for (int r = 0; r < 16; ++r) acc[t][r] = 0.f;

  for (int m0 = 0; m0 < N; m0 += 64) {
    __syncthreads();  // prior iteration's frag reads complete

    // ---- DMA: each wave copies 13 of the 52 1KB frags (both subtiles) ----
    {
      const unsigned char* gb = wblob + (size_t)((m0 >> 5) * FRAGS_PER_MT) * 1024 + ln * 16;
#pragma unroll
      for (int jj = 0; jj < 13; ++jj) {
        int jg = 13 * w + jj;
        __builtin_amdgcn_global_load_lds(
            (const void __attribute__((address_space(1)))*)(gb + (size_t)jg * 1024),
            (void __attribute__((address_space(3)))*)&L[jg * 512], 16, 0, 0);
      }
    }
    __syncthreads();  // compiler drains vmcnt before barrier -> frags visible

    // ---- QK^T: S^T = Vnorm^T * Qnorm, 3-MFMA hi/lo split ----
    f32x16 S;
#pragma unroll
    for (int r = 0; r < 16; ++r) S[r] = 0.f;
    const short* vbase = &L[st * (FRAGS_PER_MT * 512)];
#pragma unroll
    for (int k = 0; k < 8; ++k) {
      bf16x8 ah = *(const bf16x8*)&vbase[k * 512 + ln * 8];
      bf16x8 al = *(const bf16x8*)&vbase[(8 + k) * 512 + ln * 8];
      S = __builtin_amdgcn_mfma_f32_32x32x16_bf16(al, Qh[k], S, 0, 0, 0);
      S = __builtin_amdgcn_mfma_f32_32x32x16_bf16(ah, Ql[k], S, 0, 0, 0);
      S = __builtin_amdgcn_mfma_f32_32x32x16_bf16(ah, Qh[k], S, 0, 0, 0);
    }

    // ---- P = exp(100*S-60), RNE hi, own-wave P frags (no barrier) ----
#pragma unroll
    for (int q = 0; q < 4; ++q) {
      float p0 = __expf(fmaf(S[4 * q + 0], 100.0f, -60.0f));
      float p1 = __expf(fmaf(S[4 * q + 1], 100.0f, -60.0f));
      float p2 = __expf(fmaf(S[4 * q + 2], 100.0f, -60.0f));
      float p3 = __expf(fmaf(S[4 * q + 3], 100.0f, -60.0f));
      int2 a;
      a.x = rne2(p0, p1);
      a.y = rne2(p2, p3);
      *(int2*)&L[OFF_P + w * 1024 + (q >> 1) * 512 + (l31 + 32 * (q & 1)) * 8 + h * 4] = a;
    }

    // ---- PV: acc[t] += Vcm[t] * Phi ----
#pragma unroll
    for (int s2 = 0; s2 < 2; ++s2) {
      bf16x8 bh = *(const bf16x8*)&L[OFF_P + w * 1024 + s2 * 512 + ln * 8];
#pragma unroll
      for (int t = 0; t < 5; ++t) {
        bf16x8 va = *(const bf16x8*)&vbase[(16 + 2 * t + s2) * 512 + ln * 8];
        acc[t] = __builtin_amdgcn_mfma_f32_32x32x16_bf16(va, bh, acc[t], 0, 0, 0);
      }
    }
  }

  // ---- cross-subtile reduction + epilogue ----
  __syncthreads();
  float* red = (float*)&L[0];
  if (st == 1) {
#pragma unroll
    for (int t = 0; t < 5; ++t)
#pragma unroll
      for (int r = 0; r < 16; ++r)
        red[wn * 5120 + t * 1024 + r * 64 + ln] = acc[t][r];
  }
  __syncthreads();

  if (st == 0) {
#pragma unroll
    for (int t = 0; t < 5; ++t)
#pragma unroll
      for (int r = 0; r < 16; ++r)
        acc[t][r] += red[wn * 5120 + t * 1024 + r * 64 + ln];

    float ssqd = 0.f, dotr = 0.f;
#pragma unroll
    for (int t = 0; t < 4; ++t) {
#pragma unroll
      for (int r = 0; r < 16; ++r) {
        int c = 32 * t + (r & 3) + 8 * (r >> 2) + 4 * h;
        float d = acc[t][r];
        ssqd = fmaf(d, d, ssqd);
        dotr = fmaf(d, srcd[(size_t)c * N + nn], dotr);
      }
    }
    ssqd += __shfl_xor(ssqd, 32);
    dotr += __shfl_xor(dotr, 32);
    if (h == 0) {
      float x = acc[4][0], y = acc[4][1], wv = acc[4][2], Ld = acc[4][3];
      float invL = 1.0f / Ld;
      float nrm = fmaxf(sqrtf(ssqd), 1e-30f);
      float score = dotr / (nrm * 128.0f);
      float sw = wtsp[(size_t)sb * N + nn];
      out[(size_t)p * 2 * N + nn] = x * invL;
      out[(size_t)p * 2 * N + N + nn] = y * invL;
      out[(size_t)(BP * 2 * N) + (size_t)p * N + nn] =
          0.5f * (score + 1.0f) * sw * wv * invL;
    }
  }
}

// ================= fallback (round-3) path, used if ws too small ===========
#define OFF_VMH3 0
#define OFF_VML3 8192
#define OFF_VCM3 16384
#define OFF_PH3 26624
#define LDS3_SHORTS 30720

__global__ __launch_bounds__(256, 2) void kmain_v3(
    const float* __restrict__ coords, const float* __restrict__ wtsp,
    const float* __restrict__ desc, const float* __restrict__ inv,
    float* __restrict__ out) {
  const int ntile = blockIdx.x;
  const int p = blockIdx.y;
  const int sb = 2 * p, tb = 2 * p + 1;
  const int n0 = ntile * TN;
  const int tid = threadIdx.x;
  const int w = tid >> 6;
  const int ln = tid & 63;
  const int l31 = ln & 31;
  const int h = ln >> 5;
  const int wn = w & 1;
  const int st = w >> 1;
  const int pt = wn * 64 + ln;

  __shared__ __align__(16) short L[LDS3_SHORTS];

  const float* srcd = desc + (size_t)sb * C * N;
  const float* tgtd = desc + (size_t)tb * C * N;
  const float* invtg = inv + tb * N;
  const float* tcx = coords + (size_t)tb * 2 * N;
  const float* tcy = tcx + N;
  const float* twp = wtsp + (size_t)tb * N;
  const int nn = n0 + 32 * wn + l31;

  float ssq = 0.f;
#pragma unroll
  for (int k = 0; k < 8; ++k) {
    int cb = 16 * k + 8 * h;
#pragma unroll
    for (int i = 0; i < 8; ++i) {
      float v = srcd[(size_t)(cb + i) * N + nn];
      ssq = fmaf(v, v, ssq);
    }
  }
  ssq += __shfl_xor(ssq, 32);
  float invs = 1.0f / fmaxf(sqrtf(ssq), 1e-12f);

  bf16x8 Qh[8], Ql[8];
#pragma unroll
  for (int k = 0; k < 8; ++k) {
    int cb = 16 * k + 8 * h;
    bf16x8 qh, ql;
#pragma unroll
    for (int i = 0; i < 8; ++i) {
      float v = srcd[(size_t)(cb + i) * N + nn] * invs;
      unsigned short hs = bf16rnd(v);
      unsigned short ls = bf16rnd(v - bf16up(hs));
      qh[i] = (short)hs;
      ql[i] = (short)ls;
    }
    Qh[k] = qh;
    Ql[k] = ql;
  }

  {
    int* z = (int*)&L[OFF_VCM3];
    for (int i = tid; i < 1024; i += 256) {
      int sI = i >> 9, j = i & 511;
      z[sI * 2560 + 2048 + j] = 0;
    }
  }

  f32x16 acc[5];
#pragma unroll
  for (int t = 0; t < 5; ++t)
#pragma unroll
    for (int r = 0; r < 16; ++r) acc[t][r] = 0.f;

  const int er = pt & 3, ehh = (pt >> 2) & 1, esf = pt >> 3;
  const float* erp = (er == 0) ? tcx : (er == 1) ? tcy : twp;

  float vm[32];
  float invm = 0.f;
  float4 exv0 = make_float4(1, 1, 1, 1), exv1 = exv0;

  auto prefetch = [&](int ms0) {
#pragma unroll
    for (int k = 0; k < 4; ++k) {
      int cb = 16 * (2 * k + wn) + 8 * h;
#pragma unroll
      for (int i = 0; i < 8; ++i)
        vm[k * 8 + i] = tgtd[(size_t)(cb + i) * N + ms0 + l31];
    }
    invm = invtg[ms0 + l31];
    if (pt < 16 && er < 3) {
      int mb = ms0 + 16 * esf + 8 * ehh;
      exv0 = *(const float4*)&erp[mb];
      exv1 = *(const float4*)&erp[mb + 4];
    }
  };

  prefetch(32 * st);

  for (int m0 = 0; m0 < N; m0 += 64) {
    const int ms0 = m0 + 32 * st;
    float4 vc[8];
#pragma unroll
    for (int it = 0; it < 8; ++it) {
      int e = pt + 128 * it, c = e >> 3, mq = e & 7;
      vc[it] = *(const float4*)&tgtd[(size_t)c * N + ms0 + 4 * mq];
    }
#pragma unroll
    for (int k = 0; k < 4; ++k) {
      int kk = 2 * k + wn;
      int hw[4], lw[4];
#pragma unroll
      for (int j = 0; j < 4; ++j) {
        float v0 = vm[k * 8 + 2 * j] * invm;
        float v1 = vm[k * 8 + 2 * j + 1] * invm;
        hw[j] = trunc2(v0, v1);
        lw[j] = trunc2(truncres(v0), truncres(v1));
      }
      *(int4*)&L[OFF_VMH3 + st * 4096 + kk * 512 + ln * 8] =
          make_int4(hw[0], hw[1], hw[2], hw[3]);
      *(int4*)&L[OFF_VML3 + st * 4096 + kk * 512 + ln * 8] =
          make_int4(lw[0], lw[1], lw[2], lw[3]);
    }
#pragma unroll
    for (int it = 0; it < 8; ++it) {
      int e = pt + 128 * it, c = e >> 3, mq = e & 7;
      float4 v = vc[it];
      int f = (c >> 5) * 2 + (mq >> 2);
      int slot = (c & 31) + 32 * ((mq >> 1) & 1);
      int2 pk;
      pk.x = rne2(v.x, v.y);
      pk.y = rne2(v.z, v.w);
      *(int2*)&L[OFF_VCM3 + st * 5120 + f * 512 + slot * 8 + (mq & 1) * 4] = pk;
    }
    if (pt < 16) {
      int4 pk;
      pk.x = rne2(exv0.x, exv0.y);
      pk.y = rne2(exv0.z, exv0.w);
      pk.z = rne2(exv1.x, exv1.y);
      pk.w = rne2(exv1.z, exv1.w);
      *(int4*)&L[OFF_VCM3 + st * 5120 + (8 + esf) * 512 + (er + 32 * ehh) * 8] = pk;
    }
    __syncthreads();
    if (m0 + 64 < N) prefetch(ms0 + 64);

    f32x16 S;
#pragma unroll
    for (int r = 0; r < 16; ++r) S[r] = 0.f;
    const short* vmh = &L[OFF_VMH3 + st * 4096];
    const short* vml = &L[OFF_VML3 + st * 4096];
#pragma unroll
    for (int k = 0; k < 8; ++k) {
      bf16x8 ah = *(const bf16x8*)&vmh[k * 512 + ln * 8];
      bf16x8 al = *(const bf16x8*)&vml[k * 512 + ln * 8];
      S = __builtin_amdgcn_mfma_f32_32x32x16_bf16(al, Qh[k], S, 0, 0, 0);
      S = __builtin_amdgcn_mfma_f32_32x32x16_bf16(ah, Ql[k], S, 0, 0, 0);
      S = __builtin_amdgcn_mfma_f32_32x32x16_bf16(ah, Qh[k], S, 0, 0, 0);
    }
#pragma unroll
    for (int q = 0; q < 4; ++q) {
      float p0 = __expf(fmaf(S[4 * q + 0], 100.0f, -60.0f));
      float p1 = __expf(fmaf(S[4 * q + 1], 100.0f, -60.0f));
      float p2 = __expf(fmaf(S[4 * q + 2], 100.0f, -60.0f));
      float p3 = __expf(fmaf(S[4 * q + 3], 100.0f, -60.0f));
      int2 a;
      a.x = rne2(p0, p1);
      a.y = rne2(p2, p3);
      *(int2*)&L[OFF_PH3 + w * 1024 + (q >> 1) * 512 + (l31 + 32 * (q & 1)) * 8 + h * 4] = a;
    }
#pragma unroll
    for (int s2 = 0; s2 < 2; ++s2) {
      bf16x8 bh = *(const bf16x8*)&L[OFF_PH3 + w * 1024 + s2 * 512 + ln * 8];
#pragma unroll
      for (int t = 0; t < 5; ++t) {
        bf16x8 va = *(const bf16x8*)&L[OFF_VCM3 + st * 5120 + (2 * t + s2) * 512 + ln * 8];
        acc[t] = __builtin_amdgcn_mfma_f32_32x32x16_bf16(va, bh, acc[t], 0, 0, 0);
      }
    }
    __syncthreads();
  }

  float* red = (float*)&L[0];
  if (st == 1) {
#pragma unroll
    for (int t = 0; t < 5; ++t)
#pragma unroll
      for (int r = 0; r < 16; ++r)
        red[wn * 5120 + t * 1024 + r * 64 + ln] = acc[t][r];
  }
  __syncthreads();
  if (st == 0) {
#pragma unroll
    for (int t = 0; t < 5; ++t)
#pragma unroll
      for (int r = 0; r < 16; ++r)
        acc[t][r] += red[wn * 5120 + t * 1024 + r * 64 + ln];
    float ssqd = 0.f, dotr = 0.f;
#pragma unroll
    for (int t = 0; t < 4; ++t) {
#pragma unroll
      for (int r = 0; r < 16; ++r) {
        int c = 32 * t + (r & 3) + 8 * (r >> 2) + 4 * h;
        float d = acc[t][r];
        ssqd = fmaf(d, d, ssqd);
        dotr = fmaf(d, srcd[(size_t)c * N + nn], dotr);
      }
    }
    ssqd += __shfl_xor(ssqd, 32);
    dotr += __shfl_xor(dotr, 32);
    if (h == 0) {
      float x = acc[4][0], y = acc[4][1], wv = acc[4][2], Ld = acc[4][3];
      float invL = 1.0f / Ld;
      float nrm = fmaxf(sqrtf(ssqd), 1e-30f);
      float score = dotr / (nrm * 128.0f);
      float sw = wtsp[(size_t)sb * N + nn];
      out[(size_t)p * 2 * N + nn] = x * invL;
      out[(size_t)p * 2 * N + N + nn] = y * invL;
      out[(size_t)(BP * 2 * N) + (size_t)p * N + nn] =
          0.5f * (score + 1.0f) * sw * wv * invL;
    }
  }
}

extern "C" void kernel_launch(void* const* d_in, const int* in_sizes, int n_in,
                              void* d_out, int out_size, void* d_ws, size_t ws_size,
                              hipStream_t stream) {
  const float* coords = (const float*)d_in[0];  // [16][2][4096]
  const float* wts = (const float*)d_in[1];     // [16][1][4096]
  const float* desc = (const float*)d_in[2];    // [16][128][4096]
  float* out = (float*)d_out;                   // [8][2][4096] ++ [8][1][4096]
  float* inv = (float*)d_ws;                    // [16][4096] inv-norms
  unsigned char* blob = (unsigned char*)d_ws + PREP_OFF;

  knorm_inv<<<dim3(N / 256, BP), 256, 0, stream>>>(desc, inv);
  if (ws_size >= PREP_OFF + BLOB_BYTES) {
    kprep<<<dim3(128, BP), 256, 0, stream>>>(coords, wts, desc, inv, blob);
    kmain<<<dim3(N / TN, BP), 256, 0, stream>>>(wts, desc, blob, out);
  } else {
    kmain_v3<<<dim3(N / TN, BP), 256, 0, stream>>>(coords, wts, desc, inv, out);
  }
}

// Round 5
// 208.085 us; speedup vs baseline: 6.8597x; 1.1645x over previous
//
#include <hip/hip_runtime.h>
#include <math.h>

#define C 128
#define N 4096
#define BP 8
#define TN 64

typedef __attribute__((ext_vector_type(8))) short bf16x8;
typedef __attribute__((ext_vector_type(16))) float f32x16;
typedef __attribute__((ext_vector_type(4))) int i32x4;
typedef __attribute__((ext_vector_type(16))) int i32x16;

// ---------- ws layout ----------
// [0, 64KB)   inv-norms float[16][4096] (fallback path only)
// [64KB, ...) fragment blob: [pair][mt=128][18 frags][1KB]
//   frag 0..3  = Vm hi (QK^T A, normalized tgt, i8 hi of 15-bit fixed)
//   frag 4..7  = Vm lo (i8 lo)
//   frag 8..15 = Vcm hi (PV A, raw tgt desc, bf16 RNE)
//   frag 16..17= extras rows x/y/w/1 (bf16, rest zero)
#define PREP_OFF 65536
#define FRAGS_PER_MT 18
#define BLOB_BYTES ((size_t)BP * 128 * FRAGS_PER_MT * 1024)

__device__ __forceinline__ unsigned short bf16rnd(float x) {
  unsigned u = __float_as_uint(x);
  u += 0x7fffu + ((u >> 16) & 1u);
  return (unsigned short)(u >> 16);
}
__device__ __forceinline__ float bf16up(unsigned short h) {
  return __uint_as_float(((unsigned)h) << 16);
}
__device__ __forceinline__ int rne2(float x, float y) {
  unsigned ux = __float_as_uint(x); ux += 0x7fffu + ((ux >> 16) & 1u);
  unsigned uy = __float_as_uint(y); uy += 0x7fffu + ((uy >> 16) & 1u);
  return (int)__builtin_amdgcn_perm(uy, ux, 0x07060302u);
}
__device__ __forceinline__ int trunc2(float x, float y) {
  return (int)__builtin_amdgcn_perm(__float_as_uint(y), __float_as_uint(x), 0x07060302u);
}
__device__ __forceinline__ float truncres(float x) {
  return x - __uint_as_float(__float_as_uint(x) & 0xffff0000u);
}
__device__ __forceinline__ int pk4(int a, int b, int c, int d) {
  return (a & 255) | ((b & 255) << 8) | ((c & 255) << 16) | ((d & 255) << 24);
}

// Kernel 1 (fallback only): inv[b][n] = 1/max(||desc[b,:,n]||,1e-12), odd b
__global__ __launch_bounds__(256) void knorm_inv(const float* __restrict__ desc,
                                                 float* __restrict__ inv) {
  int n = blockIdx.x * 256 + threadIdx.x;
  int b = 2 * blockIdx.y + 1;
  const float* d = desc + (size_t)b * C * N + n;
  float ssq = 0.f;
#pragma unroll 8
  for (int c = 0; c < C; ++c) {
    float v = d[(size_t)c * N];
    ssq = fmaf(v, v, ssq);
  }
  inv[b * N + n] = 1.0f / fmaxf(sqrtf(ssq), 1e-12f);
}

// Kernel 1b: one-shot conversion of tgt tiles into fragment-order blobs.
// Computes tgt inv-norms in-block (fused knorm). Block = (mt, pair).
__global__ __launch_bounds__(256) void kprep(
    const float* __restrict__ coords, const float* __restrict__ wtsp,
    const float* __restrict__ desc, unsigned char* __restrict__ blob) {
  const int mt = blockIdx.x;  // 0..127
  const int p = blockIdx.y;   // 0..7
  const int tb = 2 * p + 1;
  const int m0 = mt * 32;
  const int t = threadIdx.x;
  const int ks = t >> 6;        // 0..3 (k-step of K=32)
  const int h = (t >> 5) & 1;   // lane-half within frag
  const int l31 = t & 31;       // m within subtile

  __shared__ float rss[8][32];

  const float* tgtd = desc + (size_t)tb * C * N;
  unsigned char* bl = blob + ((size_t)(p * 128 + mt) * FRAGS_PER_MT) * 1024;

  // load this thread's 16 channels of column m0+l31, partial sum-of-squares
  float vr[16];
  float part = 0.f;
#pragma unroll
  for (int i = 0; i < 16; ++i) {
    float v = tgtd[(size_t)(32 * ks + 16 * h + i) * N + m0 + l31];
    vr[i] = v;
    part = fmaf(v, v, part);
  }
  rss[ks * 2 + h][l31] = part;
  __syncthreads();
  float ssq = 0.f;
#pragma unroll
  for (int u = 0; u < 8; ++u) ssq += rss[u][l31];
  const float invm = 1.0f / fmaxf(sqrtf(ssq), 1e-12f);

  // quantize to 15-bit fixed (q = hi*256 + lo), pack i8 frags
  {
    int hb[16], lb[16];
#pragma unroll
    for (int i = 0; i < 16; ++i) {
      int q = (int)rintf(vr[i] * invm * 16384.f);
      int hi = (q + 128) >> 8;
      hb[i] = hi;
      lb[i] = q - (hi << 8);
    }
    int4 ph = make_int4(pk4(hb[0], hb[1], hb[2], hb[3]), pk4(hb[4], hb[5], hb[6], hb[7]),
                        pk4(hb[8], hb[9], hb[10], hb[11]), pk4(hb[12], hb[13], hb[14], hb[15]));
    int4 pl = make_int4(pk4(lb[0], lb[1], lb[2], lb[3]), pk4(lb[4], lb[5], lb[6], lb[7]),
                        pk4(lb[8], lb[9], lb[10], lb[11]), pk4(lb[12], lb[13], lb[14], lb[15]));
    int lane = 32 * h + l31;
    *(int4*)(bl + (size_t)ks * 1024 + lane * 16) = ph;
    *(int4*)(bl + (size_t)(4 + ks) * 1024 + lane * 16) = pl;
  }

  // Vcm desc frags 8..15 (PV A fragment order, bf16 RNE)
#pragma unroll
  for (int it = 0; it < 4; ++it) {
    int e = t + 256 * it;  // 0..1023 float4 granules
    int c = e >> 3, mq = e & 7;
    float4 v = *(const float4*)&tgtd[(size_t)c * N + m0 + 4 * mq];
    int f = (c >> 5) * 2 + (mq >> 2);
    int slot = (c & 31) + 32 * ((mq >> 1) & 1);
    int2 pk;
    pk.x = rne2(v.x, v.y);
    pk.y = rne2(v.z, v.w);
    *(int2*)(bl + (size_t)(8 + f) * 1024 + slot * 16 + (mq & 1) * 8) = pk;
  }

  // extras frags 16,17: rows 0..3 = x,y,w,1; all other rows zero
  if (t < 128) {
    int fe = t >> 6, slot = t & 63, r = slot & 31, hh = slot >> 5;
    int4 pk = make_int4(0, 0, 0, 0);
    if (r < 4) {
      const float* rp = (r == 0)   ? coords + (size_t)tb * 2 * N
                        : (r == 1) ? coords + (size_t)tb * 2 * N + N
                                   : wtsp + (size_t)tb * N;
      int mb = m0 + 16 * fe + 8 * hh;
      float v[8];
#pragma unroll
      for (int i = 0; i < 8; ++i) v[i] = (r == 3) ? 1.0f : rp[mb + i];
      pk.x = rne2(v[0], v[1]);
      pk.y = rne2(v[2], v[3]);
      pk.z = rne2(v[4], v[5]);
      pk.w = rne2(v[6], v[7]);
    }
    *(int4*)(bl + (size_t)(16 + fe) * 1024 + slot * 16) = pk;
  }
}

// ---------- main kernel: double-buffered DMA, i8 QK, shfl-P ----------
// LDS: 2 bufs x 2 subtiles x 18 frags x 1KB = 72 KB -> 2 blocks/CU.
#define BUF_SHORTS (2 * FRAGS_PER_MT * 512)  // 18432
#define LDS_SHORTS (2 * BUF_SHORTS)

__global__ __launch_bounds__(256, 2) void kmain(
    const float* __restrict__ wtsp, const float* __restrict__ desc,
    const unsigned char* __restrict__ blob, float* __restrict__ out) {
  const int ntile = blockIdx.x;
  const int p = blockIdx.y;
  const int sb = 2 * p;
  const int n0 = ntile * TN;
  const int tid = threadIdx.x;
  const int w = tid >> 6;
  const int ln = tid & 63;
  const int l31 = ln & 31;
  const int h = ln >> 5;
  const int wn = w & 1;   // n-slab
  const int st = w >> 1;  // m-subtile

  __shared__ __align__(16) short L[LDS_SHORTS];

  const float* srcd = desc + (size_t)sb * C * N;
  const unsigned char* wblob = blob + (size_t)p * 128 * FRAGS_PER_MT * 1024;
  const int nn = n0 + 32 * wn + l31;

  // ---- Q setup: norm + resident i8 hi/lo B-fragments ----
  float ssq = 0.f;
#pragma unroll
  for (int ks = 0; ks < 4; ++ks) {
#pragma unroll
    for (int i = 0; i < 16; ++i) {
      float v = srcd[(size_t)(32 * ks + 16 * h + i) * N + nn];
      ssq = fmaf(v, v, ssq);
    }
  }
  ssq += __shfl_xor(ssq, 32);
  const float invs = 1.0f / fmaxf(sqrtf(ssq), 1e-12f);

  i32x4 Qhi[4], Qlo[4];
#pragma unroll
  for (int ks = 0; ks < 4; ++ks) {
    int hb[16], lb[16];
#pragma unroll
    for (int i = 0; i < 16; ++i) {
      float v = srcd[(size_t)(32 * ks + 16 * h + i) * N + nn] * invs;
      int q = (int)rintf(v * 16384.f);
      int hi = (q + 128) >> 8;
      hb[i] = hi;
      lb[i] = q - (hi << 8);
    }
    i32x4 qh = {pk4(hb[0], hb[1], hb[2], hb[3]), pk4(hb[4], hb[5], hb[6], hb[7]),
                pk4(hb[8], hb[9], hb[10], hb[11]), pk4(hb[12], hb[13], hb[14], hb[15])};
    i32x4 ql = {pk4(lb[0], lb[1], lb[2], lb[3]), pk4(lb[4], lb[5], lb[6], lb[7]),
                pk4(lb[8], lb[9], lb[10], lb[11]), pk4(lb[12], lb[13], lb[14], lb[15])};
    Qhi[ks] = qh;
    Qlo[ks] = ql;
  }

  f32x16 acc[5];
#pragma unroll
  for (int t = 0; t < 5; ++t)
#pragma unroll
    for (int r = 0; r < 16; ++r) acc[t][r] = 0.f;

  // DMA: wave copies 9 of 36 frags (2 consecutive mt subtiles) per iter
  auto issue_dma = [&](int it, int bufb) {
    const unsigned char* gsrc = wblob + (size_t)(it * 2 * FRAGS_PER_MT) * 1024 + ln * 16;
    short* dst = &L[bufb * BUF_SHORTS];
#pragma unroll
    for (int jj = 0; jj < 9; ++jj) {
      int jg = 9 * w + jj;
      __builtin_amdgcn_global_load_lds(
          (const void __attribute__((address_space(1)))*)(gsrc + (size_t)jg * 1024),
          (void __attribute__((address_space(3)))*)&dst[jg * 512], 16, 0, 0);
    }
  };

  issue_dma(0, 0);
  __syncthreads();

  for (int it = 0; it < 64; ++it) {
    const int cb = it & 1;
    if (it + 1 < 64) issue_dma(it + 1, cb ^ 1);  // latency hidden by compute

    const short* vbase = &L[cb * BUF_SHORTS + st * (FRAGS_PER_MT * 512)];

    // ---- QK^T: 15-bit fixed i8, exact 4-MFMA (hh, hl+lh, ll) ----
    i32x16 Shh, Sx, Sll;
#pragma unroll
    for (int r = 0; r < 16; ++r) { Shh[r] = 0; Sx[r] = 0; Sll[r] = 0; }
#pragma unroll
    for (int ks = 0; ks < 4; ++ks) {
      i32x4 ah = *(const i32x4*)&vbase[ks * 512 + ln * 8];
      i32x4 al = *(const i32x4*)&vbase[(4 + ks) * 512 + ln * 8];
      Shh = __builtin_amdgcn_mfma_i32_32x32x32_i8(ah, Qhi[ks], Shh, 0, 0, 0);
      Sx = __builtin_amdgcn_mfma_i32_32x32x32_i8(ah, Qlo[ks], Sx, 0, 0, 0);
      Sx = __builtin_amdgcn_mfma_i32_32x32x32_i8(al, Qhi[ks], Sx, 0, 0, 0);
      Sll = __builtin_amdgcn_mfma_i32_32x32x32_i8(al, Qlo[ks], Sll, 0, 0, 0);
    }

    // ---- P = exp(100*dot - 60); dot = (65536*Shh + 256*Sx + Sll)/2^28 ----
    int pp[8], xpp[8];
#pragma unroll
    for (int q = 0; q < 4; ++q) {
      float pv[4];
#pragma unroll
      for (int j = 0; j < 4; ++j) {
        int r = 4 * q + j;
        int tot = (Shh[r] << 8) + Sx[r];  // |tot| < 2^27.1
        float sf = fmaf((float)tot, 256.f, (float)Sll[r]);
        pv[j] = __expf(fmaf(sf, 3.7252903e-07f, -60.0f));  // 100/2^28
      }
      pp[2 * q] = rne2(pv[0], pv[1]);
      pp[2 * q + 1] = rne2(pv[2], pv[3]);
    }
#pragma unroll
    for (int j = 0; j < 8; ++j) xpp[j] = __shfl_xor(pp[j], 32);

    // ---- PV: B-frags assembled from C-quads via cross-half swap ----
#pragma unroll
    for (int s2 = 0; s2 < 2; ++s2) {
      int4 bi;
      if (h == 0)
        bi = make_int4(pp[4 * s2 + 0], pp[4 * s2 + 1], xpp[4 * s2 + 0], xpp[4 * s2 + 1]);
      else
        bi = make_int4(xpp[4 * s2 + 2], xpp[4 * s2 + 3], pp[4 * s2 + 2], pp[4 * s2 + 3]);
      bf16x8 bh = __builtin_bit_cast(bf16x8, bi);
#pragma unroll
      for (int t = 0; t < 5; ++t) {
        bf16x8 va = *(const bf16x8*)&vbase[(8 + 2 * t + s2) * 512 + ln * 8];
        acc[t] = __builtin_amdgcn_mfma_f32_32x32x16_bf16(va, bh, acc[t], 0, 0, 0);
      }
    }

    __syncthreads();
  }

  // ---- cross-subtile reduction + epilogue ----
  float* red = (float*)&L[0];
  if (st == 1) {
#pragma unroll
    for (int t = 0; t < 5; ++t)
#pragma unroll
      for (int r = 0; r < 16; ++r)
        red[wn * 5120 + t * 1024 + r * 64 + ln] = acc[t][r];
  }
  __syncthreads();

  if (st == 0) {
#pragma unroll
    for (int t = 0; t < 5; ++t)
#pragma unroll
      for (int r = 0; r < 16; ++r)
        acc[t][r] += red[wn * 5120 + t * 1024 + r * 64 + ln];

    float ssqd = 0.f, dotr = 0.f;
#pragma unroll
    for (int t = 0; t < 4; ++t) {
#pragma unroll
      for (int r = 0; r < 16; ++r) {
        int c = 32 * t + (r & 3) + 8 * (r >> 2) + 4 * h;
        float d = acc[t][r];
        ssqd = fmaf(d, d, ssqd);
        dotr = fmaf(d, srcd[(size_t)c * N + nn], dotr);
      }
    }
    ssqd += __shfl_xor(ssqd, 32);
    dotr += __shfl_xor(dotr, 32);
    if (h == 0) {
      float x = acc[4][0], y = acc[4][1], wv = acc[4][2], Ld = acc[4][3];
      float invL = 1.0f / Ld;
      float nrm = fmaxf(sqrtf(ssqd), 1e-30f);
      float score = dotr / (nrm * 128.0f);
      float sw = wtsp[(size_t)sb * N + nn];
      out[(size_t)p * 2 * N + nn] = x * invL;
      out[(size_t)p * 2 * N + N + nn] = y * invL;
      out[(size_t)(BP * 2 * N) + (size_t)p * N + nn] =
          0.5f * (score + 1.0f) * sw * wv * invL;
    }
  }
}

// ================= fallback (round-3) path, used if ws too small ===========
#define OFF_VMH3 0
#define OFF_VML3 8192
#define OFF_VCM3 16384
#define OFF_PH3 26624
#define LDS3_SHORTS 30720

__global__ __launch_bounds__(256, 2) void kmain_v3(
    const float* __restrict__ coords, const float* __restrict__ wtsp,
    const float* __restrict__ desc, const float* __restrict__ inv,
    float* __restrict__ out) {
  const int ntile = blockIdx.x;
  const int p = blockIdx.y;
  const int sb = 2 * p, tb = 2 * p + 1;
  const int n0 = ntile * TN;
  const int tid = threadIdx.x;
  const int w = tid >> 6;
  const int ln = tid & 63;
  const int l31 = ln & 31;
  const int h = ln >> 5;
  const int wn = w & 1;
  const int st = w >> 1;
  const int pt = wn * 64 + ln;

  __shared__ __align__(16) short L[LDS3_SHORTS];

  const float* srcd = desc + (size_t)sb * C * N;
  const float* tgtd = desc + (size_t)tb * C * N;
  const float* invtg = inv + tb * N;
  const float* tcx = coords + (size_t)tb * 2 * N;
  const float* tcy = tcx + N;
  const float* twp = wtsp + (size_t)tb * N;
  const int nn = n0 + 32 * wn + l31;

  float ssq = 0.f;
#pragma unroll
  for (int k = 0; k < 8; ++k) {
    int cb = 16 * k + 8 * h;
#pragma unroll
    for (int i = 0; i < 8; ++i) {
      float v = srcd[(size_t)(cb + i) * N + nn];
      ssq = fmaf(v, v, ssq);
    }
  }
  ssq += __shfl_xor(ssq, 32);
  float invs = 1.0f / fmaxf(sqrtf(ssq), 1e-12f);

  bf16x8 Qh[8], Ql[8];
#pragma unroll
  for (int k = 0; k < 8; ++k) {
    int cb = 16 * k + 8 * h;
    bf16x8 qh, ql;
#pragma unroll
    for (int i = 0; i < 8; ++i) {
      float v = srcd[(size_t)(cb + i) * N + nn] * invs;
      unsigned short hs = bf16rnd(v);
      unsigned short ls = bf16rnd(v - bf16up(hs));
      qh[i] = (short)hs;
      ql[i] = (short)ls;
    }
    Qh[k] = qh;
    Ql[k] = ql;
  }

  {
    int* z = (int*)&L[OFF_VCM3];
    for (int i = tid; i < 1024; i += 256) {
      int sI = i >> 9, j = i & 511;
      z[sI * 2560 + 2048 + j] = 0;
    }
  }

  f32x16 acc[5];
#pragma unroll
  for (int t = 0; t < 5; ++t)
#pragma unroll
    for (int r = 0; r < 16; ++r) acc[t][r] = 0.f;

  const int er = pt & 3, ehh = (pt >> 2) & 1, esf = pt >> 3;
  const float* erp = (er == 0) ? tcx : (er == 1) ? tcy : twp;

  float vm[32];
  float invm = 0.f;
  float4 exv0 = make_float4(1, 1, 1, 1), exv1 = exv0;

  auto prefetch = [&](int ms0) {
#pragma unroll
    for (int k = 0; k < 4; ++k) {
      int cb = 16 * (2 * k + wn) + 8 * h;
#pragma unroll
      for (int i = 0; i < 8; ++i)
        vm[k * 8 + i] = tgtd[(size_t)(cb + i) * N + ms0 + l31];
    }
    invm = invtg[ms0 + l31];
    if (pt < 16 && er < 3) {
      int mb = ms0 + 16 * esf + 8 * ehh;
      exv0 = *(const float4*)&erp[mb];
      exv1 = *(const float4*)&erp[mb + 4];
    }
  };

  prefetch(32 * st);

  for (int m0 = 0; m0 < N; m0 += 64) {
    const int ms0 = m0 + 32 * st;
    float4 vc[8];
#pragma unroll
    for (int it = 0; it < 8; ++it) {
      int e = pt + 128 * it, c = e >> 3, mq = e & 7;
      vc[it] = *(const float4*)&tgtd[(size_t)c * N + ms0 + 4 * mq];
    }
#pragma unroll
    for (int k = 0; k < 4; ++k) {
      int kk = 2 * k + wn;
      int hw[4], lw[4];
#pragma unroll
      for (int j = 0; j < 4; ++j) {
        float v0 = vm[k * 8 + 2 * j] * invm;
        float v1 = vm[k * 8 + 2 * j + 1] * invm;
        hw[j] = trunc2(v0, v1);
        lw[j] = trunc2(truncres(v0), truncres(v1));
      }
      *(int4*)&L[OFF_VMH3 + st * 4096 + kk * 512 + ln * 8] =
          make_int4(hw[0], hw[1], hw[2], hw[3]);
      *(int4*)&L[OFF_VML3 + st * 4096 + kk * 512 + ln * 8] =
          make_int4(lw[0], lw[1], lw[2], lw[3]);
    }
#pragma unroll
    for (int it = 0; it < 8; ++it) {
      int e = pt + 128 * it, c = e >> 3, mq = e & 7;
      float4 v = vc[it];
      int f = (c >> 5) * 2 + (mq >> 2);
      int slot = (c & 31) + 32 * ((mq >> 1) & 1);
      int2 pk;
      pk.x = rne2(v.x, v.y);
      pk.y = rne2(v.z, v.w);
      *(int2*)&L[OFF_VCM3 + st * 5120 + f * 512 + slot * 8 + (mq & 1) * 4] = pk;
    }
    if (pt < 16) {
      int4 pk;
      pk.x = rne2(exv0.x, exv0.y);
      pk.y = rne2(exv0.z, exv0.w);
      pk.z = rne2(exv1.x, exv1.y);
      pk.w = rne2(exv1.z, exv1.w);
      *(int4*)&L[OFF_VCM3 + st * 5120 + (8 + esf) * 512 + (er + 32 * ehh) * 8] = pk;
    }
    __syncthreads();
    if (m0 + 64 < N) prefetch(ms0 + 64);

    f32x16 S;
#pragma unroll
    for (int r = 0; r < 16; ++r) S[r] = 0.f;
    const short* vmh = &L[OFF_VMH3 + st * 4096];
    const short* vml = &L[OFF_VML3 + st * 4096];
#pragma unroll
    for (int k = 0; k < 8; ++k) {
      bf16x8 ah = *(const bf16x8*)&vmh[k * 512 + ln * 8];
      bf16x8 al = *(const bf16x8*)&vml[k * 512 + ln * 8];
      S = __builtin_amdgcn_mfma_f32_32x32x16_bf16(al, Qh[k], S, 0, 0, 0);
      S = __builtin_amdgcn_mfma_f32_32x32x16_bf16(ah, Ql[k], S, 0, 0, 0);
      S = __builtin_amdgcn_mfma_f32_32x32x16_bf16(ah, Qh[k], S, 0, 0, 0);
    }
#pragma unroll
    for (int q = 0; q < 4; ++q) {
      float p0 = __expf(fmaf(S[4 * q + 0], 100.0f, -60.0f));
      float p1 = __expf(fmaf(S[4 * q + 1], 100.0f, -60.0f));
      float p2 = __expf(fmaf(S[4 * q + 2], 100.0f, -60.0f));
      float p3 = __expf(fmaf(S[4 * q + 3], 100.0f, -60.0f));
      int2 a;
      a.x = rne2(p0, p1);
      a.y = rne2(p2, p3);
      *(int2*)&L[OFF_PH3 + w * 1024 + (q >> 1) * 512 + (l31 + 32 * (q & 1)) * 8 + h * 4] = a;
    }
#pragma unroll
    for (int s2 = 0; s2 < 2; ++s2) {
      bf16x8 bh = *(const bf16x8*)&L[OFF_PH3 + w * 1024 + s2 * 512 + ln * 8];
#pragma unroll
      for (int t = 0; t < 5; ++t) {
        bf16x8 va = *(const bf16x8*)&L[OFF_VCM3 + st * 5120 + (2 * t + s2) * 512 + ln * 8];
        acc[t] = __builtin_amdgcn_mfma_f32_32x32x16_bf16(va, bh, acc[t], 0, 0, 0);
      }
    }
    __syncthreads();
  }

  float* red = (float*)&L[0];
  if (st == 1) {
#pragma unroll
    for (int t = 0; t < 5; ++t)
#pragma unroll
      for (int r = 0; r < 16; ++r)
        red[wn * 5120 + t * 1024 + r * 64 + ln] = acc[t][r];
  }
  __syncthreads();
  if (st == 0) {
#pragma unroll
    for (int t = 0; t < 5; ++t)
#pragma unroll
      for (int r = 0; r < 16; ++r)
        acc[t][r] += red[wn * 5120 + t * 1024 + r * 64 + ln];
    float ssqd = 0.f, dotr = 0.f;
#pragma unroll
    for (int t = 0; t < 4; ++t) {
#pragma unroll
      for (int r = 0; r < 16; ++r) {
        int c = 32 * t + (r & 3) + 8 * (r >> 2) + 4 * h;
        float d = acc[t][r];
        ssqd = fmaf(d, d, ssqd);
        dotr = fmaf(d, srcd[(size_t)c * N + nn], dotr);
      }
    }
    ssqd += __shfl_xor(ssqd, 32);
    dotr += __shfl_xor(dotr, 32);
    if (h == 0) {
      float x = acc[4][0], y = acc[4][1], wv = acc[4][2], Ld = acc[4][3];
      float invL = 1.0f / Ld;
      float nrm = fmaxf(sqrtf(ssqd), 1e-30f);
      float score = dotr / (nrm * 128.0f);
      float sw = wtsp[(size_t)sb * N + nn];
      out[(size_t)p * 2 * N + nn] = x * invL;
      out[(size_t)p * 2 * N + N + nn] = y * invL;
      out[(size_t)(BP * 2 * N) + (size_t)p * N + nn] =
          0.5f * (score + 1.0f) * sw * wv * invL;
    }
  }
}

extern "C" void kernel_launch(void* const* d_in, const int* in_sizes, int n_in,
                              void* d_out, int out_size, void* d_ws, size_t ws_size,
                              hipStream_t stream) {
  const float* coords = (const float*)d_in[0];  // [16][2][4096]
  const float* wts = (const float*)d_in[1];     // [16][1][4096]
  const float* desc = (const float*)d_in[2];    // [16][128][4096]
  float* out = (float*)d_out;                   // [8][2][4096] ++ [8][1][4096]
  float* inv = (float*)d_ws;                    // fallback inv-norms
  unsigned char* blob = (unsigned char*)d_ws + PREP_OFF;

  if (ws_size >= PREP_OFF + BLOB_BYTES) {
    kprep<<<dim3(128, BP), 256, 0, stream>>>(coords, wts, desc, blob);
    kmain<<<dim3(N / TN, BP), 256, 0, stream>>>(wts, desc, blob, out);
  } else {
    knorm_inv<<<dim3(N / 256, BP), 256, 0, stream>>>(desc, inv);
    kmain_v3<<<dim3(N / TN, BP), 256, 0, stream>>>(coords, wts, desc, inv, out);
  }
}

// Round 6
// 185.207 us; speedup vs baseline: 7.7070x; 1.1235x over previous
//
#include <hip/hip_runtime.h>
#include <math.h>

#define C 128
#define N 4096
#define BP 8
#define TN 64

typedef __attribute__((ext_vector_type(8))) short bf16x8;
typedef __attribute__((ext_vector_type(16))) float f32x16;
typedef __attribute__((ext_vector_type(4))) int i32x4;
typedef __attribute__((ext_vector_type(16))) int i32x16;

// ---------- ws layout ----------
// [0, 64KB)   inv-norms float[16][4096] (fallback path only)
// [64KB, ...) fragment blob: [pair][mt=128][18 frags][1KB]
//   frag 0..3  = Vm hi (QK^T A, normalized tgt, i8 hi of 15-bit fixed)
//   frag 4..7  = Vm lo (i8 lo)
//   frag 8..15 = Vcm hi (PV A, raw tgt desc, bf16 RNE)
//   frag 16..17= extras rows x/y/w/1 (bf16, rest zero)
#define PREP_OFF 65536
#define FRAGS_PER_MT 18
#define SUBT_BYTES (FRAGS_PER_MT * 1024)
#define BLOB_BYTES ((size_t)BP * 128 * FRAGS_PER_MT * 1024)

__device__ __forceinline__ unsigned short bf16rnd(float x) {
  unsigned u = __float_as_uint(x);
  u += 0x7fffu + ((u >> 16) & 1u);
  return (unsigned short)(u >> 16);
}
__device__ __forceinline__ float bf16up(unsigned short h) {
  return __uint_as_float(((unsigned)h) << 16);
}
__device__ __forceinline__ int rne2(float x, float y) {
  unsigned ux = __float_as_uint(x); ux += 0x7fffu + ((ux >> 16) & 1u);
  unsigned uy = __float_as_uint(y); uy += 0x7fffu + ((uy >> 16) & 1u);
  return (int)__builtin_amdgcn_perm(uy, ux, 0x07060302u);
}
__device__ __forceinline__ int trunc2(float x, float y) {
  return (int)__builtin_amdgcn_perm(__float_as_uint(y), __float_as_uint(x), 0x07060302u);
}
__device__ __forceinline__ float truncres(float x) {
  return x - __uint_as_float(__float_as_uint(x) & 0xffff0000u);
}
__device__ __forceinline__ int pk4(int a, int b, int c, int d) {
  return (a & 255) | ((b & 255) << 8) | ((c & 255) << 16) | ((d & 255) << 24);
}

// Kernel 1 (fallback only)
__global__ __launch_bounds__(256) void knorm_inv(const float* __restrict__ desc,
                                                 float* __restrict__ inv) {
  int n = blockIdx.x * 256 + threadIdx.x;
  int b = 2 * blockIdx.y + 1;
  const float* d = desc + (size_t)b * C * N + n;
  float ssq = 0.f;
#pragma unroll 8
  for (int c = 0; c < C; ++c) {
    float v = d[(size_t)c * N];
    ssq = fmaf(v, v, ssq);
  }
  inv[b * N + n] = 1.0f / fmaxf(sqrtf(ssq), 1e-12f);
}

// Kernel 1b: one-shot conversion of tgt tiles into fragment-order blobs.
__global__ __launch_bounds__(256) void kprep(
    const float* __restrict__ coords, const float* __restrict__ wtsp,
    const float* __restrict__ desc, unsigned char* __restrict__ blob) {
  const int mt = blockIdx.x;  // 0..127
  const int p = blockIdx.y;   // 0..7
  const int tb = 2 * p + 1;
  const int m0 = mt * 32;
  const int t = threadIdx.x;
  const int ks = t >> 6;
  const int h = (t >> 5) & 1;
  const int l31 = t & 31;

  __shared__ float rss[8][32];

  const float* tgtd = desc + (size_t)tb * C * N;
  unsigned char* bl = blob + ((size_t)(p * 128 + mt) * FRAGS_PER_MT) * 1024;

  float vr[16];
  float part = 0.f;
#pragma unroll
  for (int i = 0; i < 16; ++i) {
    float v = tgtd[(size_t)(32 * ks + 16 * h + i) * N + m0 + l31];
    vr[i] = v;
    part = fmaf(v, v, part);
  }
  rss[ks * 2 + h][l31] = part;
  __syncthreads();
  float ssq = 0.f;
#pragma unroll
  for (int u = 0; u < 8; ++u) ssq += rss[u][l31];
  const float invm = 1.0f / fmaxf(sqrtf(ssq), 1e-12f);

  {
    int hb[16], lb[16];
#pragma unroll
    for (int i = 0; i < 16; ++i) {
      int q = (int)rintf(vr[i] * invm * 16384.f);
      int hi = (q + 128) >> 8;
      hb[i] = hi;
      lb[i] = q - (hi << 8);
    }
    int4 ph = make_int4(pk4(hb[0], hb[1], hb[2], hb[3]), pk4(hb[4], hb[5], hb[6], hb[7]),
                        pk4(hb[8], hb[9], hb[10], hb[11]), pk4(hb[12], hb[13], hb[14], hb[15]));
    int4 pl = make_int4(pk4(lb[0], lb[1], lb[2], lb[3]), pk4(lb[4], lb[5], lb[6], lb[7]),
                        pk4(lb[8], lb[9], lb[10], lb[11]), pk4(lb[12], lb[13], lb[14], lb[15]));
    int lane = 32 * h + l31;
    *(int4*)(bl + (size_t)ks * 1024 + lane * 16) = ph;
    *(int4*)(bl + (size_t)(4 + ks) * 1024 + lane * 16) = pl;
  }

#pragma unroll
  for (int it = 0; it < 4; ++it) {
    int e = t + 256 * it;
    int c = e >> 3, mq = e & 7;
    float4 v = *(const float4*)&tgtd[(size_t)c * N + m0 + 4 * mq];
    int f = (c >> 5) * 2 + (mq >> 2);
    int slot = (c & 31) + 32 * ((mq >> 1) & 1);
    int2 pk;
    pk.x = rne2(v.x, v.y);
    pk.y = rne2(v.z, v.w);
    *(int2*)(bl + (size_t)(8 + f) * 1024 + slot * 16 + (mq & 1) * 8) = pk;
  }

  if (t < 128) {
    int fe = t >> 6, slot = t & 63, r = slot & 31, hh = slot >> 5;
    int4 pk = make_int4(0, 0, 0, 0);
    if (r < 4) {
      const float* rp = (r == 0)   ? coords + (size_t)tb * 2 * N
                        : (r == 1) ? coords + (size_t)tb * 2 * N + N
                                   : wtsp + (size_t)tb * N;
      int mb = m0 + 16 * fe + 8 * hh;
      float v[8];
#pragma unroll
      for (int i = 0; i < 8; ++i) v[i] = (r == 3) ? 1.0f : rp[mb + i];
      pk.x = rne2(v[0], v[1]);
      pk.y = rne2(v[2], v[3]);
      pk.z = rne2(v[4], v[5]);
      pk.w = rne2(v[6], v[7]);
    }
    *(int4*)(bl + (size_t)(16 + fe) * 1024 + slot * 16) = pk;
  }
}

// ---------- main kernel v6 ----------
// QK A-frags via double-buffered DMA LDS (16 KB/block-iter); V/extras frags
// direct global->VGPR (L1/L2 path). Sll dropped (2-accum i8 QK). 1-D grid
// with p = bid&7 so each pair's blob slice is XCD-L2 resident.
#define LDS_SHORTS 20480  // 40 KB: dbuf 2x8 KB-shorts (32 KB) + reduction reuse

__global__ __launch_bounds__(256, 2) void kmain(
    const float* __restrict__ wtsp, const float* __restrict__ desc,
    const unsigned char* __restrict__ blob, float* __restrict__ out) {
  const int bid = blockIdx.x;
  const int p = bid & 7;        // XCD-affine pair
  const int ntile = bid >> 3;
  const int sb = 2 * p;
  const int n0 = ntile * TN;
  const int tid = threadIdx.x;
  const int w = tid >> 6;
  const int ln = tid & 63;
  const int l31 = ln & 31;
  const int h = ln >> 5;
  const int wn = w & 1;   // n-slab
  const int st = w >> 1;  // m-subtile

  __shared__ __align__(16) short L[LDS_SHORTS];

  const float* srcd = desc + (size_t)sb * C * N;
  const unsigned char* wblob = blob + (size_t)p * 128 * SUBT_BYTES;
  const int nn = n0 + 32 * wn + l31;

  // ---- Q setup: norm + resident i8 hi/lo B-fragments ----
  float ssq = 0.f;
#pragma unroll
  for (int ks = 0; ks < 4; ++ks) {
#pragma unroll
    for (int i = 0; i < 16; ++i) {
      float v = srcd[(size_t)(32 * ks + 16 * h + i) * N + nn];
      ssq = fmaf(v, v, ssq);
    }
  }
  ssq += __shfl_xor(ssq, 32);
  const float invs = 1.0f / fmaxf(sqrtf(ssq), 1e-12f);

  i32x4 Qhi[4], Qlo[4];
#pragma unroll
  for (int ks = 0; ks < 4; ++ks) {
    int hb[16], lb[16];
#pragma unroll
    for (int i = 0; i < 16; ++i) {
      float v = srcd[(size_t)(32 * ks + 16 * h + i) * N + nn] * invs;
      int q = (int)rintf(v * 16384.f);
      int hi = (q + 128) >> 8;
      hb[i] = hi;
      lb[i] = q - (hi << 8);
    }
    i32x4 qh = {pk4(hb[0], hb[1], hb[2], hb[3]), pk4(hb[4], hb[5], hb[6], hb[7]),
                pk4(hb[8], hb[9], hb[10], hb[11]), pk4(hb[12], hb[13], hb[14], hb[15])};
    i32x4 ql = {pk4(lb[0], lb[1], lb[2], lb[3]), pk4(lb[4], lb[5], lb[6], lb[7]),
                pk4(lb[8], lb[9], lb[10], lb[11]), pk4(lb[12], lb[13], lb[14], lb[15])};
    Qhi[ks] = qh;
    Qlo[ks] = ql;
  }

  f32x16 acc[5];
#pragma unroll
  for (int t = 0; t < 5; ++t)
#pragma unroll
    for (int r = 0; r < 16; ++r) acc[t][r] = 0.f;

  i32x16 zz;
#pragma unroll
  for (int r = 0; r < 16; ++r) zz[r] = 0;

  // DMA: wave copies 4 of 16 QK frags (2 subtiles x 8) per iter
  auto issue_dma = [&](int it2, int bufb) {
    const unsigned char* s0 = wblob + (size_t)(it2 * 2) * SUBT_BYTES + ln * 16;
#pragma unroll
    for (int jj = 0; jj < 4; ++jj) {
      int jg = 4 * w + jj;
      const unsigned char* src = s0 + (size_t)(jg >> 3) * SUBT_BYTES + (size_t)(jg & 7) * 1024;
      __builtin_amdgcn_global_load_lds(
          (const void __attribute__((address_space(1)))*)src,
          (void __attribute__((address_space(3)))*)&L[bufb * 8192 + jg * 512], 16, 0, 0);
    }
  };
  // direct V loads: 5 frags of s2-group
  auto loadV = [&](int it2, int s2, bf16x8* V) {
    const unsigned char* vb =
        wblob + (size_t)(it2 * 2 + st) * SUBT_BYTES + (size_t)(8 + s2) * 1024 + ln * 16;
#pragma unroll
    for (int t = 0; t < 5; ++t) V[t] = *(const bf16x8*)(vb + (size_t)(2 * t) * 1024);
  };

  issue_dma(0, 0);
  bf16x8 V0[5], V1[5];
  loadV(0, 0, V0);
  __syncthreads();

  for (int it = 0; it < 64; ++it) {
    const int cb = it & 1;
    if (it < 63) issue_dma(it + 1, cb ^ 1);

    const short* vb = &L[cb * 8192 + st * 4096];

    // ---- QK^T: i8 hi/lo, 3 MFMAs per ks (hh, hl, lh) ----
    i32x16 Shh, Sx;
    {
      i32x4 ah = *(const i32x4*)&vb[0 * 512 + ln * 8];
      i32x4 al = *(const i32x4*)&vb[4 * 512 + ln * 8];
      Shh = __builtin_amdgcn_mfma_i32_32x32x32_i8(ah, Qhi[0], zz, 0, 0, 0);
      Sx = __builtin_amdgcn_mfma_i32_32x32x32_i8(ah, Qlo[0], zz, 0, 0, 0);
      Sx = __builtin_amdgcn_mfma_i32_32x32x32_i8(al, Qhi[0], Sx, 0, 0, 0);
    }
#pragma unroll
    for (int ks = 1; ks < 4; ++ks) {
      i32x4 ah = *(const i32x4*)&vb[ks * 512 + ln * 8];
      i32x4 al = *(const i32x4*)&vb[(4 + ks) * 512 + ln * 8];
      Shh = __builtin_amdgcn_mfma_i32_32x32x32_i8(ah, Qhi[ks], Shh, 0, 0, 0);
      Sx = __builtin_amdgcn_mfma_i32_32x32x32_i8(ah, Qlo[ks], Sx, 0, 0, 0);
      Sx = __builtin_amdgcn_mfma_i32_32x32x32_i8(al, Qhi[ks], Sx, 0, 0, 0);
    }

    // V group 1 for this iter (latency hidden behind exp phase)
    loadV(it, 1, V1);

    // ---- P = exp(100*dot - 60); dot ~= (Shh*256 + Sx)*256/2^28 ----
    int pp[8], xpp[8];
#pragma unroll
    for (int q = 0; q < 4; ++q) {
      float pv[4];
#pragma unroll
      for (int j = 0; j < 4; ++j) {
        int r = 4 * q + j;
        int tot = (Shh[r] << 8) + Sx[r];
        pv[j] = __expf(fmaf((float)tot, 9.5367431640625e-5f, -60.0f));
      }
      pp[2 * q] = rne2(pv[0], pv[1]);
      pp[2 * q + 1] = rne2(pv[2], pv[3]);
    }
#pragma unroll
    for (int j = 0; j < 8; ++j) xpp[j] = __shfl_xor(pp[j], 32);

    // ---- PV s2=0 ----
    {
      int4 bi;
      if (h == 0)
        bi = make_int4(pp[0], pp[1], xpp[0], xpp[1]);
      else
        bi = make_int4(xpp[2], xpp[3], pp[2], pp[3]);
      bf16x8 bh = __builtin_bit_cast(bf16x8, bi);
#pragma unroll
      for (int t = 0; t < 5; ++t)
        acc[t] = __builtin_amdgcn_mfma_f32_32x32x16_bf16(V0[t], bh, acc[t], 0, 0, 0);
    }

    // prefetch next iter's V group 0
    {
      int itn = (it < 63) ? it + 1 : 63;
      loadV(itn, 0, V0);
    }

    // ---- PV s2=1 ----
    {
      int4 bi;
      if (h == 0)
        bi = make_int4(pp[4], pp[5], xpp[4], xpp[5]);
      else
        bi = make_int4(xpp[6], xpp[7], pp[6], pp[7]);
      bf16x8 bh = __builtin_bit_cast(bf16x8, bi);
#pragma unroll
      for (int t = 0; t < 5; ++t)
        acc[t] = __builtin_amdgcn_mfma_f32_32x32x16_bf16(V1[t], bh, acc[t], 0, 0, 0);
    }

    __syncthreads();  // dbuf handoff: cb readers done, cb^1 DMA landed
  }

  // ---- cross-subtile reduction + epilogue ----
  float* red = (float*)&L[0];
  if (st == 1) {
#pragma unroll
    for (int t = 0; t < 5; ++t)
#pragma unroll
      for (int r = 0; r < 16; ++r)
        red[wn * 5120 + t * 1024 + r * 64 + ln] = acc[t][r];
  }
  __syncthreads();

  if (st == 0) {
#pragma unroll
    for (int t = 0; t < 5; ++t)
#pragma unroll
      for (int r = 0; r < 16; ++r)
        acc[t][r] += red[wn * 5120 + t * 1024 + r * 64 + ln];

    float ssqd = 0.f, dotr = 0.f;
#pragma unroll
    for (int t = 0; t < 4; ++t) {
#pragma unroll
      for (int r = 0; r < 16; ++r) {
        int c = 32 * t + (r & 3) + 8 * (r >> 2) + 4 * h;
        float d = acc[t][r];
        ssqd = fmaf(d, d, ssqd);
        dotr = fmaf(d, srcd[(size_t)c * N + nn], dotr);
      }
    }
    ssqd += __shfl_xor(ssqd, 32);
    dotr += __shfl_xor(dotr, 32);
    if (h == 0) {
      float x = acc[4][0], y = acc[4][1], wv = acc[4][2], Ld = acc[4][3];
      float invL = 1.0f / Ld;
      float nrm = fmaxf(sqrtf(ssqd), 1e-30f);
      float score = dotr / (nrm * 128.0f);
      float sw = wtsp[(size_t)sb * N + nn];
      out[(size_t)p * 2 * N + nn] = x * invL;
      out[(size_t)p * 2 * N + N + nn] = y * invL;
      out[(size_t)(BP * 2 * N) + (size_t)p * N + nn] =
          0.5f * (score + 1.0f) * sw * wv * invL;
    }
  }
}

// ================= fallback (round-3) path, used if ws too small ===========
#define OFF_VMH3 0
#define OFF_VML3 8192
#define OFF_VCM3 16384
#define OFF_PH3 26624
#define LDS3_SHORTS 30720

__global__ __launch_bounds__(256, 2) void kmain_v3(
    const float* __restrict__ coords, const float* __restrict__ wtsp,
    const float* __restrict__ desc, const float* __restrict__ inv,
    float* __restrict__ out) {
  const int ntile = blockIdx.x;
  const int p = blockIdx.y;
  const int sb = 2 * p, tb = 2 * p + 1;
  const int n0 = ntile * TN;
  const int tid = threadIdx.x;
  const int w = tid >> 6;
  const int ln = tid & 63;
  const int l31 = ln & 31;
  const int h = ln >> 5;
  const int wn = w & 1;
  const int st = w >> 1;
  const int pt = wn * 64 + ln;

  __shared__ __align__(16) short L[LDS3_SHORTS];

  const float* srcd = desc + (size_t)sb * C * N;
  const float* tgtd = desc + (size_t)tb * C * N;
  const float* invtg = inv + tb * N;
  const float* tcx = coords + (size_t)tb * 2 * N;
  const float* tcy = tcx + N;
  const float* twp = wtsp + (size_t)tb * N;
  const int nn = n0 + 32 * wn + l31;

  float ssq = 0.f;
#pragma unroll
  for (int k = 0; k < 8; ++k) {
    int cb = 16 * k + 8 * h;
#pragma unroll
    for (int i = 0; i < 8; ++i) {
      float v = srcd[(size_t)(cb + i) * N + nn];
      ssq = fmaf(v, v, ssq);
    }
  }
  ssq += __shfl_xor(ssq, 32);
  float invs = 1.0f / fmaxf(sqrtf(ssq), 1e-12f);

  bf16x8 Qh[8], Ql[8];
#pragma unroll
  for (int k = 0; k < 8; ++k) {
    int cb = 16 * k + 8 * h;
    bf16x8 qh, ql;
#pragma unroll
    for (int i = 0; i < 8; ++i) {
      float v = srcd[(size_t)(cb + i) * N + nn] * invs;
      unsigned short hs = bf16rnd(v);
      unsigned short ls = bf16rnd(v - bf16up(hs));
      qh[i] = (short)hs;
      ql[i] = (short)ls;
    }
    Qh[k] = qh;
    Ql[k] = ql;
  }

  {
    int* z = (int*)&L[OFF_VCM3];
    for (int i = tid; i < 1024; i += 256) {
      int sI = i >> 9, j = i & 511;
      z[sI * 2560 + 2048 + j] = 0;
    }
  }

  f32x16 acc[5];
#pragma unroll
  for (int t = 0; t < 5; ++t)
#pragma unroll
    for (int r = 0; r < 16; ++r) acc[t][r] = 0.f;

  const int er = pt & 3, ehh = (pt >> 2) & 1, esf = pt >> 3;
  const float* erp = (er == 0) ? tcx : (er == 1) ? tcy : twp;

  float vm[32];
  float invm = 0.f;
  float4 exv0 = make_float4(1, 1, 1, 1), exv1 = exv0;

  auto prefetch = [&](int ms0) {
#pragma unroll
    for (int k = 0; k < 4; ++k) {
      int cb = 16 * (2 * k + wn) + 8 * h;
#pragma unroll
      for (int i = 0; i < 8; ++i)
        vm[k * 8 + i] = tgtd[(size_t)(cb + i) * N + ms0 + l31];
    }
    invm = invtg[ms0 + l31];
    if (pt < 16 && er < 3) {
      int mb = ms0 + 16 * esf + 8 * ehh;
      exv0 = *(const float4*)&erp[mb];
      exv1 = *(const float4*)&erp[mb + 4];
    }
  };

  prefetch(32 * st);

  for (int m0 = 0; m0 < N; m0 += 64) {
    const int ms0 = m0 + 32 * st;
    float4 vc[8];
#pragma unroll
    for (int it = 0; it < 8; ++it) {
      int e = pt + 128 * it, c = e >> 3, mq = e & 7;
      vc[it] = *(const float4*)&tgtd[(size_t)c * N + ms0 + 4 * mq];
    }
#pragma unroll
    for (int k = 0; k < 4; ++k) {
      int kk = 2 * k + wn;
      int hw[4], lw[4];
#pragma unroll
      for (int j = 0; j < 4; ++j) {
        float v0 = vm[k * 8 + 2 * j] * invm;
        float v1 = vm[k * 8 + 2 * j + 1] * invm;
        hw[j] = trunc2(v0, v1);
        lw[j] = trunc2(truncres(v0), truncres(v1));
      }
      *(int4*)&L[OFF_VMH3 + st * 4096 + kk * 512 + ln * 8] =
          make_int4(hw[0], hw[1], hw[2], hw[3]);
      *(int4*)&L[OFF_VML3 + st * 4096 + kk * 512 + ln * 8] =
          make_int4(lw[0], lw[1], lw[2], lw[3]);
    }
#pragma unroll
    for (int it = 0; it < 8; ++it) {
      int e = pt + 128 * it, c = e >> 3, mq = e & 7;
      float4 v = vc[it];
      int f = (c >> 5) * 2 + (mq >> 2);
      int slot = (c & 31) + 32 * ((mq >> 1) & 1);
      int2 pk;
      pk.x = rne2(v.x, v.y);
      pk.y = rne2(v.z, v.w);
      *(int2*)&L[OFF_VCM3 + st * 5120 + f * 512 + slot * 8 + (mq & 1) * 4] = pk;
    }
    if (pt < 16) {
      int4 pk;
      pk.x = rne2(exv0.x, exv0.y);
      pk.y = rne2(exv0.z, exv0.w);
      pk.z = rne2(exv1.x, exv1.y);
      pk.w = rne2(exv1.z, exv1.w);
      *(int4*)&L[OFF_VCM3 + st * 5120 + (8 + esf) * 512 + (er + 32 * ehh) * 8] = pk;
    }
    __syncthreads();
    if (m0 + 64 < N) prefetch(ms0 + 64);

    f32x16 S;
#pragma unroll
    for (int r = 0; r < 16; ++r) S[r] = 0.f;
    const short* vmh = &L[OFF_VMH3 + st * 4096];
    const short* vml = &L[OFF_VML3 + st * 4096];
#pragma unroll
    for (int k = 0; k < 8; ++k) {
      bf16x8 ah = *(const bf16x8*)&vmh[k * 512 + ln * 8];
      bf16x8 al = *(const bf16x8*)&vml[k * 512 + ln * 8];
      S = __builtin_amdgcn_mfma_f32_32x32x16_bf16(al, Qh[k], S, 0, 0, 0);
      S = __builtin_amdgcn_mfma_f32_32x32x16_bf16(ah, Ql[k], S, 0, 0, 0);
      S = __builtin_amdgcn_mfma_f32_32x32x16_bf16(ah, Qh[k], S, 0, 0, 0);
    }
#pragma unroll
    for (int q = 0; q < 4; ++q) {
      float p0 = __expf(fmaf(S[4 * q + 0], 100.0f, -60.0f));
      float p1 = __expf(fmaf(S[4 * q + 1], 100.0f, -60.0f));
      float p2 = __expf(fmaf(S[4 * q + 2], 100.0f, -60.0f));
      float p3 = __expf(fmaf(S[4 * q + 3], 100.0f, -60.0f));
      int2 a;
      a.x = rne2(p0, p1);
      a.y = rne2(p2, p3);
      *(int2*)&L[OFF_PH3 + w * 1024 + (q >> 1) * 512 + (l31 + 32 * (q & 1)) * 8 + h * 4] = a;
    }
#pragma unroll
    for (int s2 = 0; s2 < 2; ++s2) {
      bf16x8 bh = *(const bf16x8*)&L[OFF_PH3 + w * 1024 + s2 * 512 + ln * 8];
#pragma unroll
      for (int t = 0; t < 5; ++t) {
        bf16x8 va = *(const bf16x8*)&L[OFF_VCM3 + st * 5120 + (2 * t + s2) * 512 + ln * 8];
        acc[t] = __builtin_amdgcn_mfma_f32_32x32x16_bf16(va, bh, acc[t], 0, 0, 0);
      }
    }
    __syncthreads();
  }

  float* red = (float*)&L[0];
  if (st == 1) {
#pragma unroll
    for (int t = 0; t < 5; ++t)
#pragma unroll
      for (int r = 0; r < 16; ++r)
        red[wn * 5120 + t * 1024 + r * 64 + ln] = acc[t][r];
  }
  __syncthreads();
  if (st == 0) {
#pragma unroll
    for (int t = 0; t < 5; ++t)
#pragma unroll
      for (int r = 0; r < 16; ++r)
        acc[t][r] += red[wn * 5120 + t * 1024 + r * 64 + ln];
    float ssqd = 0.f, dotr = 0.f;
#pragma unroll
    for (int t = 0; t < 4; ++t) {
#pragma unroll
      for (int r = 0; r < 16; ++r) {
        int c = 32 * t + (r & 3) + 8 * (r >> 2) + 4 * h;
        float d = acc[t][r];
        ssqd = fmaf(d, d, ssqd);
        dotr = fmaf(d, srcd[(size_t)c * N + nn], dotr);
      }
    }
    ssqd += __shfl_xor(ssqd, 32);
    dotr += __shfl_xor(dotr, 32);
    if (h == 0) {
      float x = acc[4][0], y = acc[4][1], wv = acc[4][2], Ld = acc[4][3];
      float invL = 1.0f / Ld;
      float nrm = fmaxf(sqrtf(ssqd), 1e-30f);
      float score = dotr / (nrm * 128.0f);
      float sw = wtsp[(size_t)sb * N + nn];
      out[(size_t)p * 2 * N + nn] = x * invL;
      out[(size_t)p * 2 * N + N + nn] = y * invL;
      out[(size_t)(BP * 2 * N) + (size_t)p * N + nn] =
          0.5f * (score + 1.0f) * sw * wv * invL;
    }
  }
}

extern "C" void kernel_launch(void* const* d_in, const int* in_sizes, int n_in,
                              void* d_out, int out_size, void* d_ws, size_t ws_size,
                              hipStream_t stream) {
  const float* coords = (const float*)d_in[0];  // [16][2][4096]
  const float* wts = (const float*)d_in[1];     // [16][1][4096]
  const float* desc = (const float*)d_in[2];    // [16][128][4096]
  float* out = (float*)d_out;                   // [8][2][4096] ++ [8][1][4096]
  float* inv = (float*)d_ws;                    // fallback inv-norms
  unsigned char* blob = (unsigned char*)d_ws + PREP_OFF;

  if (ws_size >= PREP_OFF + BLOB_BYTES) {
    kprep<<<dim3(128, BP), 256, 0, stream>>>(coords, wts, desc, blob);
    kmain<<<dim3((N / TN) * BP), 256, 0, stream>>>(wts, desc, blob, out);
  } else {
    knorm_inv<<<dim3(N / 256, BP), 256, 0, stream>>>(desc, inv);
    kmain_v3<<<dim3(N / TN, BP), 256, 0, stream>>>(coords, wts, desc, inv, out);
  }
}